// Round 15
// baseline (727.333 us; speedup 1.0000x reference)
//
#include <hip/hip_runtime.h>
#include <hip/hip_bf16.h>

#define KNN 20
#define NEG_SLOPE 0.2f

constexpr int BB = 8;
constexpr int NN = 1024;
constexpr int MM = 1024;

typedef short bf16x8 __attribute__((ext_vector_type(8)));
typedef float f32x4 __attribute__((ext_vector_type(4)));
typedef double f64x4 __attribute__((ext_vector_type(4)));
typedef unsigned long long u64;

// ================= top-20 selection via exact u64 keys =================
__device__ __forceinline__ u64 pack_key64(double d, int j) {
  u64 u = (u64)__double_as_longlong(d);
  u = (u & 0x8000000000000000ULL) ? ~u : (u | 0x8000000000000000ULL);
  return (u & ~(u64)1023) | (u64)(1023 - j);
}

// Per-wave top-20: each lane holds 16 keys; Batcher odd-even mergesort (desc),
// then 20 extraction rounds (wave-max + winner-lane shift). Exact, no fallback.
__device__ __forceinline__ void topk20_u64(u64 (&s)[16], int lane, int* op) {
#pragma unroll
  for (int p = 1; p < 16; p <<= 1) {
#pragma unroll
    for (int k = p; k >= 1; k >>= 1) {
#pragma unroll
      for (int j = k % p; j + k < 16; j += 2 * k) {
#pragma unroll
        for (int i = 0; i < k; ++i) {
          int a = j + i, b = j + i + k;
          if (b < 16 && (a / (2 * p)) == (b / (2 * p))) {
            u64 hi = s[a] > s[b] ? s[a] : s[b];
            u64 lo = s[a] > s[b] ? s[b] : s[a];
            s[a] = hi;
            s[b] = lo;
          }
        }
      }
    }
  }
#pragma unroll
  for (int r = 0; r < KNN; ++r) {
    u64 win = s[0];
#pragma unroll
    for (int off = 32; off > 0; off >>= 1) {
      u64 o = __shfl_xor(win, off, 64);
      win = o > win ? o : win;
    }
    if (lane == 0) op[r] = 1023 - (int)(win & (u64)1023);
    if (s[0] == win) {
#pragma unroll
      for (int i = 0; i < 15; ++i) s[i] = s[i + 1];
      s[15] = 0ULL;
    }
  }
}

// ======== f64 MFMA layout self-probe + decode, fused (one wave, ~3us) ========
__global__ void k_probe_mfma(int* __restrict__ rowt, int* __restrict__ colt,
                             int* __restrict__ flag) {
  __shared__ int cnt[256];
  __shared__ int oksh;
  int tid = threadIdx.x;  // 64 threads
  if (tid == 0) oksh = 1;
  for (int e = tid; e < 256; e += 64) cnt[e] = 0;
  __syncthreads();
  int lane = tid & 63;
  f64x4 z = {0.0, 0.0, 0.0, 0.0};
  double ai = (double)(lane & 15);
  double p3 = 1.0, p5 = 1.0;
  int kq = lane >> 4;
  for (int t = 0; t < kq; ++t) { p3 *= 3.0; p5 *= 5.0; }
  f64x4 d1 = __builtin_amdgcn_mfma_f64_16x16x4f64(ai, 1.0, z, 0, 0, 0);
  f64x4 d2 = __builtin_amdgcn_mfma_f64_16x16x4f64(1.0, ai, z, 0, 0, 0);
  f64x4 d3 = __builtin_amdgcn_mfma_f64_16x16x4f64(p3, p5, z, 0, 0, 0);
  bool ok = true;
  int ri[4], ci[4];
#pragma unroll
  for (int r = 0; r < 4; ++r) {
    double va = d1[r], vb = d2[r], vp = d3[r];
    int i = (int)(va * 0.25);
    int j = (int)(vb * 0.25);
    bool e_ok = (i >= 0) && (i < 16) && (j >= 0) && (j < 16) &&
                (va == 4.0 * (double)i) && (vb == 4.0 * (double)j) && (vp == 3616.0);
    if (e_ok) {
      atomicAdd(&cnt[i * 16 + j], 1);
    } else {
      ok = false;
      i = 0;
      j = 0;
    }
    ri[r] = i;
    ci[r] = j;
  }
  if (!ok) atomicExch(&oksh, 0);
  __syncthreads();
  bool bij = true;
  for (int e = tid; e < 256; e += 64)
    if (cnt[e] != 1) bij = false;
  if (!bij) atomicExch(&oksh, 0);
  __syncthreads();
#pragma unroll
  for (int r = 0; r < 4; ++r) {
    rowt[lane * 4 + r] = ri[r];
    colt[lane * 4 + r] = ci[r];
  }
  if (tid == 0) *flag = oksh;
}

// ---------------- elementwise f32 -> f64 cast (channel-major kept) ----------------
__global__ __launch_bounds__(256) void k_cvt_f64(
    const float* __restrict__ in, double* __restrict__ out, int n) {
  for (int i = blockIdx.x * 256 + threadIdx.x; i < n; i += gridDim.x * 256)
    out[i] = (double)in[i];
}

// ---------------- f32 -> bf16 convert ----------------
__global__ __launch_bounds__(256) void k_cvt_bf16(
    const float* __restrict__ in, __hip_bfloat16* __restrict__ out, int n) {
  int i = blockIdx.x * 256 + threadIdx.x;
  if (i < n) out[i] = __float2bfloat16(in[i]);
}

// ------ per-point norms from CHANNEL-MAJOR features: A[b*bs + c*1024 + n] ------
template <int RECIP>
__global__ __launch_bounds__(256) void k_rowsq(
    const double* __restrict__ A, int bs, int C, double* __restrict__ sq) {
  int p = blockIdx.x * 256 + threadIdx.x;
  if (p >= BB * 1024) return;
  const double* base = A + (size_t)(p >> 10) * bs + (p & 1023);
  double s = 0.0;
  for (int c = 0; c < C; ++c) { double v = base[(size_t)c << 10]; s += v * v; }
  if (RECIP) {
    sq[p] = 1.0 / fmax(sqrt(s), 1e-12);
  } else {
    sq[p] = s;
  }
}

// ---- fused L1 knn (C=3): channel-major points in LDS, u64-key topk (exact) ----
__global__ __launch_bounds__(256) void k_knn3(
    const double* __restrict__ xs3c, const double* __restrict__ sq, int* __restrict__ idx) {
  __shared__ double P[3 * NN];  // P[c*1024 + n]
  int b = blockIdx.x;
  const double* Xb = xs3c + (size_t)b * 3 * NN;
  int tid = threadIdx.x;
  for (int t = tid; t < 3 * NN; t += 256) P[t] = Xb[t];
  __syncthreads();
  int wave = tid >> 6, lane = tid & 63;
  int i = blockIdx.y * 4 + wave;
  double xi = P[i], yi = P[1024 + i], zi = P[2048 + i];
  double sqi = sq[b * NN + i];
  u64 s[16];
#pragma unroll
  for (int m = 0; m < 16; ++m) {
    int j = m * 64 + lane;
    double d = fma(xi, P[j], 0.0);
    d = fma(yi, P[1024 + j], d);
    d = fma(zi, P[2048 + j], d);
    s[m] = pack_key64(2.0 * d - sqi - sq[b * NN + j], j);
  }
  int* op = idx + ((size_t)b * NN + i) * KNN;
  topk20_u64(s, lane, op);
}

// ---- gram, LDS-FREE (gemm5-style): ONE WAVE per WG, 64x64 tile. Channel-major
// inputs let each lane load its MFMA fragment DIRECTLY from global (L2-hot,
// 16-lane-coalesced 128B segments): a[s] = A[(c0+lq)*1024 + i0 + s*16 + lm].
// Per 4-channel step: 8 loads + 16 MFMA (1024cy) -- no LDS, no barriers, no
// staging phase. Software-pipelined one step ahead. Grid batch-SLOWEST (z) for
// per-XCD L2 residency of the B panel. Probe-decoded D tables in epilogue.
// MODE 1: D = 2*dot - sqA_i - sqB_j ; MODE 2: D = dot * rnA_i * rnB_j
template <int MODE>
__global__ __launch_bounds__(64, 2) void k_gram_u(
    const double* __restrict__ A, int bsA, const double* __restrict__ Bm, int bsB,
    const double* __restrict__ sqA, const double* __restrict__ sqB,
    u64* __restrict__ kk, int C, int b0, const int* __restrict__ rowt,
    const int* __restrict__ colt, const int* __restrict__ flag) {
  int bl = blockIdx.z;
  int bg = b0 + bl;
  int j0 = blockIdx.x * 64;
  int i0 = blockIdx.y * 64;
  const double* Ab = A + (size_t)bg * bsA;
  const double* Bb = Bm + (size_t)bg * bsB;
  int lane = threadIdx.x;
  int lm = lane & 15, lq = lane >> 4;
  if (*flag) {
    const double* pA = Ab + ((size_t)lq << 10) + i0 + lm;
    const double* pB = Bb + ((size_t)lq << 10) + j0 + lm;
    f64x4 acc[4][4] = {};
    double a_[4], b_[4], an[4], bn[4];
#pragma unroll
    for (int s = 0; s < 4; ++s) {
      a_[s] = pA[s * 16];
      b_[s] = pB[s * 16];
    }
    int nst = C >> 2;
    for (int st = 0; st < nst; ++st) {
      bool pf = (st + 1 < nst);
      if (pf) {
        pA += (size_t)4 << 10;
        pB += (size_t)4 << 10;
#pragma unroll
        for (int s = 0; s < 4; ++s) {
          an[s] = pA[s * 16];
          bn[s] = pB[s * 16];
        }
      }
#pragma unroll
      for (int si = 0; si < 4; ++si)
#pragma unroll
        for (int sj = 0; sj < 4; ++sj)
          acc[si][sj] =
              __builtin_amdgcn_mfma_f64_16x16x4f64(a_[si], b_[sj], acc[si][sj], 0, 0, 0);
      if (pf) {
#pragma unroll
        for (int s = 0; s < 4; ++s) {
          a_[s] = an[s];
          b_[s] = bn[s];
        }
      }
    }
    int rta[4], cta[4];
#pragma unroll
    for (int r = 0; r < 4; ++r) {
      rta[r] = rowt[lane * 4 + r];
      cta[r] = colt[lane * 4 + r];
    }
#pragma unroll
    for (int si = 0; si < 4; ++si) {
#pragma unroll
      for (int sj = 0; sj < 4; ++sj) {
#pragma unroll
        for (int r = 0; r < 4; ++r) {
          int i = i0 + si * 16 + rta[r];
          int j = j0 + sj * 16 + cta[r];
          double v = acc[si][sj][r];
          if (MODE == 1)
            v = 2.0 * v - sqA[(size_t)bg * NN + i] - sqB[(size_t)bg * MM + j];
          if (MODE == 2) v = v * sqA[(size_t)bg * NN + i] * sqB[(size_t)bg * MM + j];
          kk[((size_t)bl * NN + i) * MM + j] = pack_key64(v, j);
        }
      }
    }
  } else {
    // correctness fallback (probe failed): channel-major VALU, 8x8 per lane
    int lr = lane >> 3, lc = lane & 7;
    double acc2[8][8] = {};
    for (int c = 0; c < C; ++c) {
      double aa[8], bb[8];
#pragma unroll
      for (int t = 0; t < 8; ++t) {
        aa[t] = Ab[((size_t)c << 10) + i0 + lr * 8 + t];
        bb[t] = Bb[((size_t)c << 10) + j0 + lc * 8 + t];
      }
#pragma unroll
      for (int ii = 0; ii < 8; ++ii)
#pragma unroll
        for (int jj = 0; jj < 8; ++jj)
          acc2[ii][jj] = fma(aa[ii], bb[jj], acc2[ii][jj]);
    }
    for (int ii = 0; ii < 8; ++ii) {
      int i = i0 + lr * 8 + ii;
      double qa = sqA[(size_t)bg * NN + i];
      for (int jj = 0; jj < 8; ++jj) {
        int j = j0 + lc * 8 + jj;
        double v = acc2[ii][jj];
        if (MODE == 1) v = 2.0 * v - qa - sqB[(size_t)bg * MM + j];
        if (MODE == 2) v = v * qa * sqB[(size_t)bg * MM + j];
        kk[((size_t)bl * NN + i) * MM + j] = pack_key64(v, j);
      }
    }
  }
}

// ---- symmetric euclid gram (A==B, layers 2/3): triangular 136-block grid,
// LDS-free direct-fragment inner loop; off-diagonal tiles write mirrored key.
__global__ __launch_bounds__(64, 2) void k_gram_sym(
    const double* __restrict__ A, int bsA, const double* __restrict__ sqA,
    u64* __restrict__ kk, int C, int b0, const int* __restrict__ rowt,
    const int* __restrict__ colt, const int* __restrict__ flag) {
  int p = blockIdx.x;  // 0..135 triangular pair index
  int r = (int)((sqrtf(8.f * p + 1.f) - 1.f) * 0.5f);
  while ((r + 1) * (r + 2) / 2 <= p) ++r;
  while (r * (r + 1) / 2 > p) --r;
  int cc = p - r * (r + 1) / 2;
  int i0 = r * 64, j0 = cc * 64;
  int bl = blockIdx.y;
  int bg = b0 + bl;
  const double* Ab = A + (size_t)bg * bsA;
  int lane = threadIdx.x;
  int lm = lane & 15, lq = lane >> 4;
  if (*flag) {
    const double* pA = Ab + ((size_t)lq << 10) + i0 + lm;
    const double* pB = Ab + ((size_t)lq << 10) + j0 + lm;
    f64x4 acc[4][4] = {};
    double a_[4], b_[4], an[4], bn[4];
#pragma unroll
    for (int s = 0; s < 4; ++s) {
      a_[s] = pA[s * 16];
      b_[s] = pB[s * 16];
    }
    int nst = C >> 2;
    for (int st = 0; st < nst; ++st) {
      bool pf = (st + 1 < nst);
      if (pf) {
        pA += (size_t)4 << 10;
        pB += (size_t)4 << 10;
#pragma unroll
        for (int s = 0; s < 4; ++s) {
          an[s] = pA[s * 16];
          bn[s] = pB[s * 16];
        }
      }
#pragma unroll
      for (int si = 0; si < 4; ++si)
#pragma unroll
        for (int sj = 0; sj < 4; ++sj)
          acc[si][sj] =
              __builtin_amdgcn_mfma_f64_16x16x4f64(a_[si], b_[sj], acc[si][sj], 0, 0, 0);
      if (pf) {
#pragma unroll
        for (int s = 0; s < 4; ++s) {
          a_[s] = an[s];
          b_[s] = bn[s];
        }
      }
    }
    int rta[4], cta[4];
#pragma unroll
    for (int r_ = 0; r_ < 4; ++r_) {
      rta[r_] = rowt[lane * 4 + r_];
      cta[r_] = colt[lane * 4 + r_];
    }
    bool mir = (i0 != j0);
#pragma unroll
    for (int si = 0; si < 4; ++si) {
#pragma unroll
      for (int sj = 0; sj < 4; ++sj) {
#pragma unroll
        for (int r_ = 0; r_ < 4; ++r_) {
          int i = i0 + si * 16 + rta[r_];
          int j = j0 + sj * 16 + cta[r_];
          double v = 2.0 * acc[si][sj][r_] - sqA[(size_t)bg * NN + i] -
                     sqA[(size_t)bg * NN + j];
          kk[((size_t)bl * NN + i) * MM + j] = pack_key64(v, j);
          if (mir) kk[((size_t)bl * NN + j) * MM + i] = pack_key64(v, i);
        }
      }
    }
  } else {
    int lr = lane >> 3, lc = lane & 7;
    double acc2[8][8] = {};
    for (int c = 0; c < C; ++c) {
      double aa[8], bb[8];
#pragma unroll
      for (int t = 0; t < 8; ++t) {
        aa[t] = Ab[((size_t)c << 10) + i0 + lr * 8 + t];
        bb[t] = Ab[((size_t)c << 10) + j0 + lc * 8 + t];
      }
#pragma unroll
      for (int ii = 0; ii < 8; ++ii)
#pragma unroll
        for (int jj = 0; jj < 8; ++jj)
          acc2[ii][jj] = fma(aa[ii], bb[jj], acc2[ii][jj]);
    }
    bool mir = (i0 != j0);
    for (int ii = 0; ii < 8; ++ii) {
      int i = i0 + lr * 8 + ii;
      double qa = sqA[(size_t)bg * NN + i];
      for (int jj = 0; jj < 8; ++jj) {
        int j = j0 + lc * 8 + jj;
        double v = 2.0 * acc2[ii][jj] - qa - sqA[(size_t)bg * NN + j];
        kk[((size_t)bl * NN + i) * MM + j] = pack_key64(v, j);
        if (mir) kk[((size_t)bl * NN + j) * MM + i] = pack_key64(v, i);
      }
    }
  }
}

// ------- top-20 per row from exact u64 keys; no fallback -------
__global__ __launch_bounds__(256) void k_topk(const u64* __restrict__ kk,
                                              int* __restrict__ idx, int b0) {
  int wave = threadIdx.x >> 6;
  int lane = threadIdx.x & 63;
  int bl = blockIdx.x;
  int row = blockIdx.y * 4 + wave;
  const u64* rp = kk + ((size_t)bl * NN + row) * MM;
  u64 s[16];
#pragma unroll
  for (int m = 0; m < 16; ++m) s[m] = rp[m * 64 + lane];
  int* op = idx + ((size_t)(b0 + bl) * NN + row) * KNN;
  topk20_u64(s, lane, op);
}

// --- fused per-point feature matmul (f64), both modes, CHANNEL-MAJOR sources ---
// mode 0: out0[b,j,o] = sum_c src0[b][c][j]*w[o,c]
// mode 1: out1[b,j,o] = sum_c src1[b][c][j]*(w[o,C+c]-w[o,c])
// 4-wave (256-thread 1-D block), barrier-per-K-block, MFMA w/ probe tables.
__global__ __launch_bounds__(256) void k_featmm2(
    const double* __restrict__ src0, int bs0, int Np0,
    const double* __restrict__ src1, int bs1,
    const float* __restrict__ w, int CW,
    double* __restrict__ out0, double* __restrict__ out1, int C, int O,
    const int* __restrict__ rowt, const int* __restrict__ colt,
    const int* __restrict__ flag) {
  __shared__ double As[16][68];
  __shared__ double Ws[16][68];
  int nbo = O >> 6;
  int b = blockIdx.x;
  int mode = blockIdx.y >= nbo;
  int o0 = (blockIdx.y - (mode ? nbo : 0)) * 64;
  int j0 = blockIdx.z * 64;
  const double* src = mode ? src1 : src0;
  int bs = mode ? bs1 : bs0;
  int Np = mode ? NN : Np0;
  double* out = mode ? out1 : out0;
  int tid = threadIdx.x;
  const double* Sb = src + (size_t)b * bs;
  if (*flag) {
    int lane = tid & 63, wv = tid >> 6;
    int lm = lane & 15, lq = lane >> 4;
    f64x4 acc[4] = {};
    for (int c0 = 0; c0 < C; c0 += 16) {
      if (c0) __syncthreads();
      for (int r = 0; r < 4; ++r) {
        int li = tid + r * 256;
        // channel-major feature staging: row fastest -> coalesced
        int rowA = li & 63, kA = li >> 6;
        int cA = c0 + kA;
        As[kA][rowA] = (cA < C) ? Sb[((size_t)cA << 10) + j0 + rowA] : 0.0;
        // weight staging (row-major small): old mapping
        int row = li >> 4, k = li & 15;
        int c = c0 + k;
        double wvv = 0.0;
        if (c < C) {
          const float* wr = w + (size_t)(o0 + row) * CW;
          wvv = (mode == 0) ? (double)wr[c] : ((double)wr[C + c] - (double)wr[c]);
        }
        Ws[k][row] = wvv;
      }
      __syncthreads();
#pragma unroll
      for (int kc = 0; kc < 4; ++kc) {
        double a = As[kc * 4 + lq][wv * 16 + lm];
#pragma unroll
        for (int t = 0; t < 4; ++t) {
          double bb = Ws[kc * 4 + lq][t * 16 + lm];
          acc[t] = __builtin_amdgcn_mfma_f64_16x16x4f64(a, bb, acc[t], 0, 0, 0);
        }
      }
    }
    int rta[4], cta[4];
#pragma unroll
    for (int r = 0; r < 4; ++r) {
      rta[r] = rowt[lane * 4 + r];
      cta[r] = colt[lane * 4 + r];
    }
#pragma unroll
    for (int t = 0; t < 4; ++t) {
#pragma unroll
      for (int r = 0; r < 4; ++r) {
        int j = j0 + wv * 16 + rta[r];
        int o = o0 + t * 16 + cta[r];
        out[((size_t)b * Np + j) * O + o] = acc[t][r];
      }
    }
  } else {
    int tx = tid & 15, ty = tid >> 4;
    double acc[4][4] = {};
    for (int c0 = 0; c0 < C; c0 += 16) {
      if (c0) __syncthreads();
      for (int r = 0; r < 4; ++r) {
        int li = tid + r * 256;
        int rowA = li & 63, kA = li >> 6;
        int cA = c0 + kA;
        As[kA][rowA] = (cA < C) ? Sb[((size_t)cA << 10) + j0 + rowA] : 0.0;
        int row = li >> 4, k = li & 15;
        int c = c0 + k;
        double wvv = 0.0;
        if (c < C) {
          const float* wr = w + (size_t)(o0 + row) * CW;
          wvv = (mode == 0) ? (double)wr[c] : ((double)wr[C + c] - (double)wr[c]);
        }
        Ws[k][row] = wvv;
      }
      __syncthreads();
#pragma unroll
      for (int k = 0; k < 16; ++k) {
        double a_[4], b_[4];
#pragma unroll
        for (int ii = 0; ii < 4; ++ii) a_[ii] = As[k][ty * 4 + ii];
#pragma unroll
        for (int jj = 0; jj < 4; ++jj) b_[jj] = Ws[k][tx * 4 + jj];
#pragma unroll
        for (int ii = 0; ii < 4; ++ii)
#pragma unroll
          for (int jj = 0; jj < 4; ++jj)
            acc[ii][jj] = fma(a_[ii], b_[jj], acc[ii][jj]);
      }
    }
    for (int ii = 0; ii < 4; ++ii) {
      int j = j0 + ty * 4 + ii;
      double* op = &out[((size_t)b * Np + j) * O + o0 + tx * 4];
      double2 v0, v1;
      v0.x = acc[ii][0];
      v0.y = acc[ii][1];
      v1.x = acc[ii][2];
      v1.y = acc[ii][3];
      *(double2*)op = v0;
      *(double2*)(op + 2) = v1;
    }
  }
}

// ---- layer-5 GEMM via bf16 MFMA: ONE WAVE per WG, 64x64 tile, K=512 unrolled ----
__global__ __launch_bounds__(64, 2) void k_gemm5_mfma(
    const __hip_bfloat16* __restrict__ cath, const __hip_bfloat16* __restrict__ w5h,
    float* __restrict__ out) {
  int b = blockIdx.x;
  int j0 = blockIdx.y * 64;
  int o0 = blockIdx.z * 64;
  int lane = threadIdx.x;
  int m = lane & 15;
  int quad = lane >> 4;
  const __hip_bfloat16* arow = cath + ((size_t)(b * NN + j0 + m)) * 512 + quad * 8;
  const __hip_bfloat16* brow = w5h + ((size_t)(o0 + m)) * 512 + quad * 8;
  f32x4 acc[4][4] = {};
#pragma unroll
  for (int c0 = 0; c0 < 512; c0 += 32) {
    bf16x8 a[4], bb[4];
#pragma unroll
    for (int s = 0; s < 4; ++s) {
      a[s] = *(const bf16x8*)(arow + (size_t)s * 16 * 512 + c0);
      bb[s] = *(const bf16x8*)(brow + (size_t)s * 16 * 512 + c0);
    }
#pragma unroll
    for (int si = 0; si < 4; ++si)
#pragma unroll
      for (int sj = 0; sj < 4; ++sj)
        acc[si][sj] =
            __builtin_amdgcn_mfma_f32_16x16x32_bf16(a[si], bb[sj], acc[si][sj], 0, 0, 0);
  }
#pragma unroll
  for (int si = 0; si < 4; ++si) {
    float* ob = &out[((size_t)(b * NN + j0 + si * 16 + quad * 4)) * 512 + o0 + m];
#pragma unroll
    for (int sj = 0; sj < 4; ++sj)
#pragma unroll
      for (int r = 0; r < 4; ++r)
        ob[(size_t)r * 512 + sj * 16] = acc[si][sj][r];
  }
}

// ------- fused gather (f64): per (n,o) max_k y, accumulate BN stats -------
// Grid (O/64, NN/16, BB): b slowest -> per-XCD L2 residency of batch slices.
__global__ __launch_bounds__(256) void k_gather(
    const double* __restrict__ u, const double* __restrict__ t, const int* __restrict__ idx,
    double* __restrict__ stats, double* __restrict__ mx, int O, int srcNp) {
  __shared__ int lidx[16 * KNN];
  __shared__ double rs[256];
  __shared__ double rq[256];
  int b = blockIdx.z;
  int n0 = blockIdx.y * 16;
  int o0 = blockIdx.x * 64;
  int tid = threadIdx.x;
  int lane = tid & 63, nsl = tid >> 6;
  for (int w = tid; w < 16 * KNN; w += 256)
    lidx[w] = idx[((size_t)b * NN + n0) * KNN + w];
  __syncthreads();
  int oo = o0 + lane;
  double s1 = 0.0, s2 = 0.0;
  for (int ns = nsl; ns < 16; ns += 4) {
    size_t row = (size_t)b * NN + n0 + ns;
    double tv = t[row * O + oo];
    double mxv = -INFINITY;
    double a1 = 0.0, a2 = 0.0;
#pragma unroll
    for (int k = 0; k < KNN; ++k) {
      int j = lidx[ns * KNN + k];
      double yv = u[((size_t)b * srcNp + j) * O + oo] + tv;
      mxv = fmax(mxv, yv);
      a1 += yv;
      a2 = fma(yv, yv, a2);
    }
    mx[row * O + oo] = mxv;
    s1 += a1;
    s2 += a2;
  }
  rs[tid] = s1;
  rq[tid] = s2;
  __syncthreads();
  if (tid < 64) {
    s1 = rs[tid] + rs[tid + 64] + rs[tid + 128] + rs[tid + 192];
    s2 = rq[tid] + rq[tid + 64] + rq[tid + 128] + rq[tid + 192];
    atomicAdd(&stats[o0 + tid], s1);
    atomicAdd(&stats[O + o0 + tid], s2);
  }
}

// --- apply BN+lrelu to stored max (f64); BN fold in LDS; catd now CHANNEL-MAJOR ---
__global__ __launch_bounds__(256) void k_bnapply(
    const double* __restrict__ mx, const double* __restrict__ u, const double* __restrict__ t,
    const int* __restrict__ idx, const double* __restrict__ stats,
    const float* __restrict__ gamma, const float* __restrict__ beta, double cnt,
    double* __restrict__ catd, __hip_bfloat16* __restrict__ cath, int coff, int O,
    int srcNp) {
  __shared__ double scs[256];
  __shared__ double scc[256];
  int tid = threadIdx.x;
  if (tid < O) {
    double mean = stats[tid] / cnt;
    double var = stats[O + tid] / cnt - mean * mean;
    if (var < 0.0) var = 0.0;
    double rstd = 1.0 / sqrt(var + 1e-5);
    double s = (double)gamma[tid] * rstd;
    scs[tid] = s;
    scc[tid] = (double)beta[tid] - mean * s;
  }
  __syncthreads();
  int i = blockIdx.x * 256 + tid;
  int total = BB * NN * O;
  if (i >= total) return;
  int oo = i % O;
  int n = (i / O) % NN;
  int b = i / (O * NN);
  double s = scs[oo], c = scc[oo];
  double v;
  if (s >= 0.0) {
    v = mx[i];
  } else {  // monotone-decreasing transform needs min_k y (never hit with gamma=1)
    double tv = t[i];
    double mn = INFINITY;
    for (int k = 0; k < KNN; ++k) {
      int j = idx[((size_t)b * NN + n) * KNN + k];
      mn = fmin(mn, u[((size_t)b * srcNp + j) * O + oo] + tv);
    }
    v = mn;
  }
  double a = s * v + c;
  a = (a >= 0.0) ? a : 0.2 * a;
  size_t ci = ((size_t)b * NN + n) * 512 + coff + oo;
  cath[ci] = __float2bfloat16((float)a);
  if (coff < 256)
    catd[(size_t)b * 256 * NN + ((size_t)(coff + oo) << 10) + n] = a;
}

// ------- layer 5 streaming stats over stored y5 (B,N,512) -------
__global__ __launch_bounds__(256) void k_stats512(
    const float* __restrict__ y5, double* __restrict__ stats) {
  int b = blockIdx.y;
  int n0 = blockIdx.x * 32;
  int tid = threadIdx.x;
  for (int part = 0; part < 2; ++part) {
    int oo = tid + part * 256;
    float a1 = 0.f, a2 = 0.f;
    for (int ns = 0; ns < 32; ++ns) {
      float v = y5[((size_t)b * NN + n0 + ns) * 512 + oo];
      a1 += v;
      a2 = fmaf(v, v, a2);
    }
    atomicAdd(&stats[oo], (double)a1);
    atomicAdd(&stats[512 + oo], (double)a2);
  }
}

// --- layer 5 finalize: BN fold in LDS, BN+lrelu on stored y5, transpose, store ---
__global__ __launch_bounds__(256) void k_final5b(
    const float* __restrict__ y5, const double* __restrict__ stats,
    const float* __restrict__ g5, const float* __restrict__ b5,
    float* __restrict__ out) {
  __shared__ float tile[64][65];
  __shared__ double scs[64];
  __shared__ double scc[64];
  int b = blockIdx.z;
  int n0 = blockIdx.x * 64;
  int o0 = blockIdx.y * 64;
  int tid = threadIdx.x;
  if (tid < 64) {
    int o = o0 + tid;
    double cnt = (double)(BB * NN);
    double mean = stats[o] / cnt;
    double var = stats[512 + o] / cnt - mean * mean;
    if (var < 0.0) var = 0.0;
    double rstd = 1.0 / sqrt(var + 1e-5);
    double s = (double)g5[o] * rstd;
    scs[tid] = s;
    scc[tid] = (double)b5[o] - mean * s;
  }
  __syncthreads();
  for (int r = 0; r < 16; ++r) {
    int li = tid + r * 256;
    int nl = li >> 6, ol = li & 63;
    float v = y5[((size_t)b * NN + n0 + nl) * 512 + o0 + ol];
    float a = (float)(scs[ol] * (double)v + scc[ol]);
    a = (a >= 0.f) ? a : NEG_SLOPE * a;
    tile[nl][ol] = a;
  }
  __syncthreads();
  for (int r = 0; r < 16; ++r) {
    int li = tid + r * 256;
    int ol = li >> 6, nl = li & 63;
    out[((size_t)b * 512 + o0 + ol) * NN + n0 + nl] = tile[nl][ol];
  }
}

// =====================================================================================
// r28 (on r27 best, 631us): gemm5 lesson applied to the f64 grams -- CHANNEL-MAJOR
// feature storage lets each lane load its MFMA fragment directly from global (L2-hot,
// 16-lane-coalesced): no LDS, no staging phase, no DS ops, barrier-free (gram was 47%
// MfmaUtil with 2.1M LDS conflicts; staging was the cap across r18-r24). One coherent
// layout change: catd=[b][256][NN], ysd/xs3c = pure f32->f64 casts (y,x are already
// channel-major -- transpose kernel DELETED). rowsq/knn3/featmm flip to channel-major
// (all reads MORE coalesced); bnapply scatters catd (L2-resident). Gram grids
// batch-slowest (r27's XCD lesson). Probe epilogue + u64-key topk untouched.
extern "C" void kernel_launch(void* const* d_in, const int* in_sizes, int n_in,
                              void* d_out, int out_size, void* d_ws, size_t ws_size,
                              hipStream_t stream) {
  const float* x = (const float*)d_in[0];
  const float* y = (const float*)d_in[1];
  const float* w1 = (const float*)d_in[2];
  const float* w2 = (const float*)d_in[3];
  const float* w3 = (const float*)d_in[4];
  const float* w4 = (const float*)d_in[5];
  const float* w5 = (const float*)d_in[6];
  const float* g1 = (const float*)d_in[7];
  const float* b1 = (const float*)d_in[8];
  const float* g2 = (const float*)d_in[9];
  const float* b2 = (const float*)d_in[10];
  const float* g3 = (const float*)d_in[11];
  const float* b3 = (const float*)d_in[12];
  const float* g4 = (const float*)d_in[13];
  const float* b4 = (const float*)d_in[14];
  const float* g5 = (const float*)d_in[15];
  const float* b5 = (const float*)d_in[16];

  char* base = (char*)d_ws;
  size_t off = 0;
  auto alloc = [&](size_t bytes) -> char* {
    char* p = base + off;
    off += (bytes + 255) & ~(size_t)255;
    return p;
  };
  double* stAll = (double*)alloc(5 * 1024 * 8);  // 5 disjoint per-layer stat slots
  double* sq = (double*)alloc((size_t)BB * NN * 8);
  double* rnx = (double*)alloc((size_t)BB * NN * 8);
  double* rny = (double*)alloc((size_t)BB * MM * 8);
  int* idxb = (int*)alloc((size_t)BB * NN * KNN * 4);
  int* rowt = (int*)alloc(256 * 4);
  int* colt = (int*)alloc(256 * 4);
  int* pflag = (int*)alloc(256);
  double* xs3c = (double*)alloc((size_t)BB * 3 * NN * 8);    // channel-major
  double* ysd = (double*)alloc((size_t)BB * 128 * MM * 8);   // channel-major
  double* catd = (double*)alloc((size_t)BB * 256 * NN * 8);  // channel-major
  __hip_bfloat16* cath = (__hip_bfloat16*)alloc((size_t)BB * NN * 512 * 2);
  __hip_bfloat16* w5h = (__hip_bfloat16*)alloc((size_t)512 * 512 * 2);
  double* uu = (double*)alloc((size_t)BB * MM * 256 * 8);  // src term (max O=256)
  double* tt = (double*)alloc((size_t)BB * NN * 256 * 8);  // center term
  size_t kkBatchBytes = (size_t)NN * MM * 8;  // 8 MB per batch (u64 keys)
  size_t avail = (ws_size > off) ? (ws_size - off) : 0;
  int CB = (int)(avail / kkBatchBytes);
  if (CB < 1) CB = 1;
  if (CB > BB) CB = BB;
  u64* KK = (u64*)alloc((size_t)CB * kkBatchBytes);
  float* y5 = (float*)uu;             // layer-5 pre-BN (16MB), uu dead by then
  double* mx = (double*)d_out;        // max_k y (f64, <=16MB == out_size)
  float* outp = (float*)d_out;

  const double cntE = (double)BB * NN * KNN;

  // sym=1: triangular symmetric euclid gram (A==B); else general MODE-2 gram (L4)
  auto knn = [&](const double* A, int bsA, const double* Bm, int bsB,
                 const double* sa, const double* sb, int C, int sym) {
    for (int b0 = 0; b0 < BB; b0 += CB) {
      int cb = (BB - b0 < CB) ? (BB - b0) : CB;
      if (sym) {
        k_gram_sym<<<dim3(136, cb), 64, 0, stream>>>(A, bsA, sa, KK, C, b0, rowt, colt,
                                                     pflag);
      } else {
        dim3 g(MM / 64, NN / 64, cb);
        k_gram_u<2><<<g, 64, 0, stream>>>(A, bsA, Bm, bsB, sa, sb, KK, C, b0, rowt,
                                          colt, pflag);
      }
      k_topk<<<dim3(cb, 256), 256, 0, stream>>>(KK, idxb, b0);
    }
  };

  auto edge_layer = [&](const double* ctr, int bsc, const double* src, int bss,
                        int srcNp, const float* w, int CW, const float* g,
                        const float* bb, int C, int O, int coff, double* st) {
    k_featmm2<<<dim3(8, 2 * (O / 64), 16), 256, 0, stream>>>(
        src, bss, srcNp, ctr, bsc, w, CW, uu, tt, C, O, rowt, colt, pflag);
    k_gather<<<dim3(O / 64, NN / 16, BB), 256, 0, stream>>>(uu, tt, idxb, st, mx, O,
                                                            srcNp);
    k_bnapply<<<(BB * NN * O + 255) / 256, 256, 0, stream>>>(
        mx, uu, tt, idxb, st, g, bb, cntE, catd, cath, coff, O, srcNp);
  };

  // ---- one memset + probe + channel-major f64 casts + w5 bf16 ----
  hipMemsetAsync(stAll, 0, 5 * 1024 * 8, stream);
  k_probe_mfma<<<1, 64, 0, stream>>>(rowt, colt, pflag);
  k_cvt_f64<<<96, 256, 0, stream>>>(x, xs3c, BB * 3 * NN);
  k_cvt_f64<<<2048, 256, 0, stream>>>(y, ysd, BB * 128 * MM);
  k_cvt_bf16<<<1024, 256, 0, stream>>>(w5, w5h, 512 * 512);

  // ---- layer 1: C=3, O=64 (fused knn, no gram) ----
  k_rowsq<0><<<32, 256, 0, stream>>>(xs3c, 3 * NN, 3, sq);
  k_knn3<<<dim3(BB, 256), 256, 0, stream>>>(xs3c, sq, idxb);
  edge_layer(xs3c, 3 * NN, xs3c, 3 * NN, NN, w1, 6, g1, b1, 3, 64, 0, stAll);

  // ---- layer 2: x1 = catd channels 0..63, C=64, O=64 ----
  k_rowsq<0><<<32, 256, 0, stream>>>(catd, 256 * NN, 64, sq);
  knn(catd, 256 * NN, catd, 256 * NN, sq, sq, 64, 1);
  edge_layer(catd, 256 * NN, catd, 256 * NN, NN, w2, 128, g2, b2, 64, 64, 64,
             stAll + 1024);

  // ---- layer 3: x2 = catd channels 64..127, C=64, O=128 ----
  k_rowsq<0><<<32, 256, 0, stream>>>(catd + 64 * NN, 256 * NN, 64, sq);
  knn(catd + 64 * NN, 256 * NN, catd + 64 * NN, 256 * NN, sq, sq, 64, 1);
  edge_layer(catd + 64 * NN, 256 * NN, catd + 64 * NN, 256 * NN, NN, w3, 128, g3, b3,
             64, 128, 128, stAll + 2048);

  // ---- layer 4 (IA): x3 = catd channels 128..255, src = ysd (cosine), C=128 ----
  k_rowsq<1><<<32, 256, 0, stream>>>(catd + 128 * NN, 256 * NN, 128, rnx);
  k_rowsq<1><<<32, 256, 0, stream>>>(ysd, 128 * MM, 128, rny);
  knn(catd + 128 * NN, 256 * NN, ysd, 128 * MM, rnx, rny, 128, 0);
  edge_layer(catd + 128 * NN, 256 * NN, ysd, 128 * MM, MM, w4, 256, g4, b4, 128, 256,
             256, stAll + 3072);

  // ---- layer 5: bf16-MFMA GEMM -> y5 (aliases uu), BN over (B,N), lrelu, transpose ----
  double* st5 = stAll + 4096;
  k_gemm5_mfma<<<dim3(8, 16, 8), 64, 0, stream>>>(cath, w5h, y5);
  k_stats512<<<dim3(32, 8), 256, 0, stream>>>(y5, st5);
  k_final5b<<<dim3(16, 8, 8), 256, 0, stream>>>(y5, st5, g5, b5, outp);
}

// Round 16
// 631.584 us; speedup vs baseline: 1.1516x; 1.1516x over previous
//
#include <hip/hip_runtime.h>
#include <hip/hip_bf16.h>

#define KNN 20
#define NEG_SLOPE 0.2f

constexpr int BB = 8;
constexpr int NN = 1024;
constexpr int MM = 1024;

typedef short bf16x8 __attribute__((ext_vector_type(8)));
typedef float f32x4 __attribute__((ext_vector_type(4)));
typedef double f64x4 __attribute__((ext_vector_type(4)));
typedef unsigned long long u64;

// ================= top-20 selection via exact u64 keys =================
// Monotone f64->u64 map, low 10 bits replaced by inverted column index.
// Key order == f64 descending order with tie -> lower idx (jax top_k semantics).
__device__ __forceinline__ u64 pack_key64(double d, int j) {
  u64 u = (u64)__double_as_longlong(d);
  u = (u & 0x8000000000000000ULL) ? ~u : (u | 0x8000000000000000ULL);
  return (u & ~(u64)1023) | (u64)(1023 - j);
}

// Per-wave top-20: each lane holds 16 keys; Batcher odd-even mergesort (desc),
// then 20 extraction rounds (wave-max + winner-lane shift). Exact, no fallback.
__device__ __forceinline__ void topk20_u64(u64 (&s)[16], int lane, int* op) {
#pragma unroll
  for (int p = 1; p < 16; p <<= 1) {
#pragma unroll
    for (int k = p; k >= 1; k >>= 1) {
#pragma unroll
      for (int j = k % p; j + k < 16; j += 2 * k) {
#pragma unroll
        for (int i = 0; i < k; ++i) {
          int a = j + i, b = j + i + k;
          if (b < 16 && (a / (2 * p)) == (b / (2 * p))) {
            u64 hi = s[a] > s[b] ? s[a] : s[b];
            u64 lo = s[a] > s[b] ? s[b] : s[a];
            s[a] = hi;
            s[b] = lo;
          }
        }
      }
    }
  }
#pragma unroll
  for (int r = 0; r < KNN; ++r) {
    u64 win = s[0];
#pragma unroll
    for (int off = 32; off > 0; off >>= 1) {
      u64 o = __shfl_xor(win, off, 64);
      win = o > win ? o : win;
    }
    if (lane == 0) op[r] = 1023 - (int)(win & (u64)1023);
    if (s[0] == win) {
#pragma unroll
      for (int i = 0; i < 15; ++i) s[i] = s[i + 1];
      s[15] = 0ULL;
    }
  }
}

// ======== f64 MFMA layout self-probe + decode, fused (one wave, ~3us) ========
__global__ void k_probe_mfma(int* __restrict__ rowt, int* __restrict__ colt,
                             int* __restrict__ flag) {
  __shared__ int cnt[256];
  __shared__ int oksh;
  int tid = threadIdx.x;  // 64 threads
  if (tid == 0) oksh = 1;
  for (int e = tid; e < 256; e += 64) cnt[e] = 0;
  __syncthreads();
  int lane = tid & 63;
  f64x4 z = {0.0, 0.0, 0.0, 0.0};
  double ai = (double)(lane & 15);
  double p3 = 1.0, p5 = 1.0;
  int kq = lane >> 4;
  for (int t = 0; t < kq; ++t) { p3 *= 3.0; p5 *= 5.0; }
  f64x4 d1 = __builtin_amdgcn_mfma_f64_16x16x4f64(ai, 1.0, z, 0, 0, 0);
  f64x4 d2 = __builtin_amdgcn_mfma_f64_16x16x4f64(1.0, ai, z, 0, 0, 0);
  f64x4 d3 = __builtin_amdgcn_mfma_f64_16x16x4f64(p3, p5, z, 0, 0, 0);
  bool ok = true;
  int ri[4], ci[4];
#pragma unroll
  for (int r = 0; r < 4; ++r) {
    double va = d1[r], vb = d2[r], vp = d3[r];
    int i = (int)(va * 0.25);
    int j = (int)(vb * 0.25);
    bool e_ok = (i >= 0) && (i < 16) && (j >= 0) && (j < 16) &&
                (va == 4.0 * (double)i) && (vb == 4.0 * (double)j) && (vp == 3616.0);
    if (e_ok) {
      atomicAdd(&cnt[i * 16 + j], 1);
    } else {
      ok = false;
      i = 0;
      j = 0;
    }
    ri[r] = i;
    ci[r] = j;
  }
  if (!ok) atomicExch(&oksh, 0);
  __syncthreads();
  bool bij = true;
  for (int e = tid; e < 256; e += 64)
    if (cnt[e] != 1) bij = false;
  if (!bij) atomicExch(&oksh, 0);
  __syncthreads();
#pragma unroll
  for (int r = 0; r < 4; ++r) {
    rowt[lane * 4 + r] = ri[r];
    colt[lane * 4 + r] = ci[r];
  }
  if (tid == 0) *flag = oksh;
}

// ---------------- transpose f32 -> f64: (B,C,Np) -> (B,Np,C) ----------------
__global__ __launch_bounds__(256) void k_transpose_d(
    const float* __restrict__ in, double* __restrict__ out, int C, int Np) {
  int total = BB * C * Np;
  for (int t = blockIdx.x * 256 + threadIdx.x; t < total; t += gridDim.x * 256) {
    int c = t % C;
    int n = (t / C) % Np;
    int b = t / (C * Np);
    out[t] = (double)in[((size_t)b * C + c) * Np + n];
  }
}

// ---------------- f32 -> bf16 convert ----------------
__global__ __launch_bounds__(256) void k_cvt_bf16(
    const float* __restrict__ in, __hip_bfloat16* __restrict__ out, int n) {
  int i = blockIdx.x * 256 + threadIdx.x;
  if (i < n) out[i] = __float2bfloat16(in[i]);
}

// ------- per-point squared norm (RECIP=0) or reciprocal norm (RECIP=1), f64 -------
template <int RECIP>
__global__ __launch_bounds__(256) void k_rowsq(
    const double* __restrict__ A, int ld, int C, double* __restrict__ sq) {
  int p = blockIdx.x * 256 + threadIdx.x;
  if (p >= BB * NN) return;
  const double* row = A + (size_t)p * ld;
  double s = 0.0;
  for (int c = 0; c < C; ++c) { double v = row[c]; s += v * v; }
  if (RECIP) {
    sq[p] = 1.0 / fmax(sqrt(s), 1e-12);
  } else {
    sq[p] = s;
  }
}

// ---- fused L1 knn (C=3): all points in LDS (f64), u64-key topk (exact) ----
__global__ __launch_bounds__(256) void k_knn3(
    const double* __restrict__ xs3, const double* __restrict__ sq, int* __restrict__ idx) {
  __shared__ double P[NN * 3];
  int b = blockIdx.x;
  const double* Xb = xs3 + (size_t)b * NN * 3;
  int tid = threadIdx.x;
  for (int t = tid; t < NN * 3; t += 256) P[t] = Xb[t];
  __syncthreads();
  int wave = tid >> 6, lane = tid & 63;
  int i = blockIdx.y * 4 + wave;
  double xi = P[i * 3], yi = P[i * 3 + 1], zi = P[i * 3 + 2];
  double sqi = sq[b * NN + i];
  u64 s[16];
#pragma unroll
  for (int m = 0; m < 16; ++m) {
    int j = m * 64 + lane;
    double d = fma(xi, P[j * 3], 0.0);
    d = fma(yi, P[j * 3 + 1], d);
    d = fma(zi, P[j * 3 + 2], d);
    s[m] = pack_key64(2.0 * d - sqi - sq[b * NN + j], j);
  }
  int* op = idx + ((size_t)b * NN + i) * KNN;
  topk20_u64(s, lane, op);
}

// ---- gram (r22-verified body): ONE WAVE per WG, 64x64 tile, K-block 8,
// barrier-free in-wave DOUBLE buffer. Grid now BATCH-SLOWEST (z): same-batch
// tiles cluster per XCD so the 2-3MB batch panels stay L2-resident (r27's
// gather lesson). Probe-decoded D tables; VALU fallback if probe failed.
// MODE 1: D=2*dot-sqA_i-sqB_j ; MODE 2: dot*rnA*rnB
template <int MODE>
__global__ __launch_bounds__(64, 2) void k_gram_u(
    const double* __restrict__ A, int lda, const double* __restrict__ Bm, int ldb,
    const double* __restrict__ sqA, const double* __restrict__ sqB,
    u64* __restrict__ kk, int C, int b0, const int* __restrict__ rowt,
    const int* __restrict__ colt, const int* __restrict__ flag) {
  __shared__ double As[2][8][69];
  __shared__ double Bs[2][8][69];
  int bl = blockIdx.z;
  int bg = b0 + bl;
  int j0 = blockIdx.x * 64;
  int i0 = blockIdx.y * 64;
  const double* Ab = A + (size_t)bg * NN * lda;
  const double* Bb = Bm + (size_t)bg * MM * ldb;
  int lane = threadIdx.x;
  if (*flag) {
    int lm = lane & 15, lq = lane >> 4;
    int k8 = lane & 7, r8 = lane >> 3;  // staging coords: k fixed, rows r8+8r
    const double* pa = Ab + (size_t)(i0 + r8) * lda + k8;
    const double* pb = Bb + (size_t)(j0 + r8) * ldb + k8;
    f64x4 acc[4][4] = {};
    double ra[8], rb[8];
    // prologue: stage K-block 0 into buffer 0
#pragma unroll
    for (int r = 0; r < 8; ++r) {
      ra[r] = pa[(size_t)(8 * r) * lda];
      rb[r] = pb[(size_t)(8 * r) * ldb];
    }
#pragma unroll
    for (int r = 0; r < 8; ++r) {
      As[0][k8][r8 + 8 * r] = ra[r];
      Bs[0][k8][r8 + 8 * r] = rb[r];
    }
    int nblk = C >> 3;
    for (int cb = 0; cb < nblk; ++cb) {
      int buf = cb & 1;
      bool pf = (cb + 1 < nblk);
      if (pf) {  // issue next block's loads; vmcnt wait lands after the MFMAs
        int c0 = (cb + 1) << 3;
#pragma unroll
        for (int r = 0; r < 8; ++r) {
          ra[r] = pa[(size_t)(8 * r) * lda + c0];
          rb[r] = pb[(size_t)(8 * r) * ldb + c0];
        }
      }
#pragma unroll
      for (int kc = 0; kc < 2; ++kc) {
        double a_[4], b_[4];
#pragma unroll
        for (int s = 0; s < 4; ++s) {
          a_[s] = As[buf][kc * 4 + lq][s * 16 + lm];
          b_[s] = Bs[buf][kc * 4 + lq][s * 16 + lm];
        }
#pragma unroll
        for (int si = 0; si < 4; ++si)
#pragma unroll
          for (int sj = 0; sj < 4; ++sj)
            acc[si][sj] = __builtin_amdgcn_mfma_f64_16x16x4f64(a_[si], b_[sj],
                                                               acc[si][sj], 0, 0, 0);
      }
      if (pf) {  // fill the other buffer (per-wave DS in-order: no barrier)
        int nb = buf ^ 1;
#pragma unroll
        for (int r = 0; r < 8; ++r) {
          As[nb][k8][r8 + 8 * r] = ra[r];
          Bs[nb][k8][r8 + 8 * r] = rb[r];
        }
      }
    }
    int rta[4], cta[4];
#pragma unroll
    for (int r = 0; r < 4; ++r) {
      rta[r] = rowt[lane * 4 + r];
      cta[r] = colt[lane * 4 + r];
    }
#pragma unroll
    for (int si = 0; si < 4; ++si) {
#pragma unroll
      for (int sj = 0; sj < 4; ++sj) {
#pragma unroll
        for (int r = 0; r < 4; ++r) {
          int i = i0 + si * 16 + rta[r];
          int j = j0 + sj * 16 + cta[r];
          double v = acc[si][sj][r];
          if (MODE == 1)
            v = 2.0 * v - sqA[(size_t)bg * NN + i] - sqB[(size_t)bg * MM + j];
          if (MODE == 2) v = v * sqA[(size_t)bg * NN + i] * sqB[(size_t)bg * MM + j];
          kk[((size_t)bl * NN + i) * MM + j] = pack_key64(v, j);
        }
      }
    }
  } else {
    int lr = lane >> 3, lc = lane & 7;  // 8x8 lane grid, 8x8 outputs each
    double acc2[8][8] = {};
    for (int c0 = 0; c0 < C; c0 += 8) {
      if (c0) __syncthreads();
      for (int r = 0; r < 8; ++r) {
        int li = lane + r * 64;
        int row = li >> 3, k = li & 7;
        As[0][k][row] = Ab[(size_t)(i0 + row) * lda + c0 + k];
        Bs[0][k][row] = Bb[(size_t)(j0 + row) * ldb + c0 + k];
      }
      __syncthreads();
#pragma unroll
      for (int k = 0; k < 8; ++k) {
        double a_[8], b_[8];
#pragma unroll
        for (int t = 0; t < 8; ++t) {
          a_[t] = As[0][k][lr * 8 + t];
          b_[t] = Bs[0][k][lc * 8 + t];
        }
#pragma unroll
        for (int ii = 0; ii < 8; ++ii)
#pragma unroll
          for (int jj = 0; jj < 8; ++jj)
            acc2[ii][jj] = fma(a_[ii], b_[jj], acc2[ii][jj]);
      }
    }
    for (int ii = 0; ii < 8; ++ii) {
      int i = i0 + lr * 8 + ii;
      double qa = sqA[(size_t)bg * NN + i];
      for (int jj = 0; jj < 8; ++jj) {
        int j = j0 + lc * 8 + jj;
        double v = acc2[ii][jj];
        if (MODE == 1) v = 2.0 * v - qa - sqB[(size_t)bg * MM + j];
        if (MODE == 2) v = v * qa * sqB[(size_t)bg * MM + j];
        kk[((size_t)bl * NN + i) * MM + j] = pack_key64(v, j);
      }
    }
  }
}

// ---- symmetric euclid gram (A==B, layers 2/3): triangular 136-block grid,
// r22-verified inner loop; batch now in grid-y (slowest) for XCD/L2 locality.
// Off-diagonal tiles also write the mirrored key kk[j][i]=pack(v,i).
__global__ __launch_bounds__(64, 2) void k_gram_sym(
    const double* __restrict__ A, int lda, const double* __restrict__ sqA,
    u64* __restrict__ kk, int C, int b0, const int* __restrict__ rowt,
    const int* __restrict__ colt, const int* __restrict__ flag) {
  __shared__ double As[2][8][69];
  __shared__ double Bs[2][8][69];
  int p = blockIdx.x;  // 0..135 triangular pair index (fastest)
  int bl = blockIdx.y;
  int bg = b0 + bl;
  int r = (int)((sqrtf(8.f * p + 1.f) - 1.f) * 0.5f);
  while ((r + 1) * (r + 2) / 2 <= p) ++r;
  while (r * (r + 1) / 2 > p) --r;
  int cc = p - r * (r + 1) / 2;
  int i0 = r * 64, j0 = cc * 64;
  const double* Ab = A + (size_t)bg * NN * lda;
  int lane = threadIdx.x;
  if (*flag) {
    int lm = lane & 15, lq = lane >> 4;
    int k8 = lane & 7, r8 = lane >> 3;
    const double* pa = Ab + (size_t)(i0 + r8) * lda + k8;
    const double* pb = Ab + (size_t)(j0 + r8) * lda + k8;
    f64x4 acc[4][4] = {};
    double ra[8], rb[8];
#pragma unroll
    for (int r_ = 0; r_ < 8; ++r_) {
      ra[r_] = pa[(size_t)(8 * r_) * lda];
      rb[r_] = pb[(size_t)(8 * r_) * lda];
    }
#pragma unroll
    for (int r_ = 0; r_ < 8; ++r_) {
      As[0][k8][r8 + 8 * r_] = ra[r_];
      Bs[0][k8][r8 + 8 * r_] = rb[r_];
    }
    int nblk = C >> 3;
    for (int cb = 0; cb < nblk; ++cb) {
      int buf = cb & 1;
      bool pf = (cb + 1 < nblk);
      if (pf) {
        int c0 = (cb + 1) << 3;
#pragma unroll
        for (int r_ = 0; r_ < 8; ++r_) {
          ra[r_] = pa[(size_t)(8 * r_) * lda + c0];
          rb[r_] = pb[(size_t)(8 * r_) * lda + c0];
        }
      }
#pragma unroll
      for (int kc = 0; kc < 2; ++kc) {
        double a_[4], b_[4];
#pragma unroll
        for (int s = 0; s < 4; ++s) {
          a_[s] = As[buf][kc * 4 + lq][s * 16 + lm];
          b_[s] = Bs[buf][kc * 4 + lq][s * 16 + lm];
        }
#pragma unroll
        for (int si = 0; si < 4; ++si)
#pragma unroll
          for (int sj = 0; sj < 4; ++sj)
            acc[si][sj] = __builtin_amdgcn_mfma_f64_16x16x4f64(a_[si], b_[sj],
                                                               acc[si][sj], 0, 0, 0);
      }
      if (pf) {
        int nb = buf ^ 1;
#pragma unroll
        for (int r_ = 0; r_ < 8; ++r_) {
          As[nb][k8][r8 + 8 * r_] = ra[r_];
          Bs[nb][k8][r8 + 8 * r_] = rb[r_];
        }
      }
    }
    int rta[4], cta[4];
#pragma unroll
    for (int r_ = 0; r_ < 4; ++r_) {
      rta[r_] = rowt[lane * 4 + r_];
      cta[r_] = colt[lane * 4 + r_];
    }
    bool mir = (i0 != j0);
#pragma unroll
    for (int si = 0; si < 4; ++si) {
#pragma unroll
      for (int sj = 0; sj < 4; ++sj) {
#pragma unroll
        for (int r_ = 0; r_ < 4; ++r_) {
          int i = i0 + si * 16 + rta[r_];
          int j = j0 + sj * 16 + cta[r_];
          double v = 2.0 * acc[si][sj][r_] - sqA[(size_t)bg * NN + i] -
                     sqA[(size_t)bg * NN + j];
          kk[((size_t)bl * NN + i) * MM + j] = pack_key64(v, j);
          if (mir) kk[((size_t)bl * NN + j) * MM + i] = pack_key64(v, i);
        }
      }
    }
  } else {
    int lr = lane >> 3, lc = lane & 7;
    double acc2[8][8] = {};
    for (int c0 = 0; c0 < C; c0 += 8) {
      if (c0) __syncthreads();
      for (int r_ = 0; r_ < 8; ++r_) {
        int li = lane + r_ * 64;
        int row = li >> 3, k = li & 7;
        As[0][k][row] = Ab[(size_t)(i0 + row) * lda + c0 + k];
        Bs[0][k][row] = Ab[(size_t)(j0 + row) * lda + c0 + k];
      }
      __syncthreads();
#pragma unroll
      for (int k = 0; k < 8; ++k) {
        double a_[8], b_[8];
#pragma unroll
        for (int t = 0; t < 8; ++t) {
          a_[t] = As[0][k][lr * 8 + t];
          b_[t] = Bs[0][k][lc * 8 + t];
        }
#pragma unroll
        for (int ii = 0; ii < 8; ++ii)
#pragma unroll
          for (int jj = 0; jj < 8; ++jj)
            acc2[ii][jj] = fma(a_[ii], b_[jj], acc2[ii][jj]);
      }
    }
    bool mir = (i0 != j0);
    for (int ii = 0; ii < 8; ++ii) {
      int i = i0 + lr * 8 + ii;
      double qa = sqA[(size_t)bg * NN + i];
      for (int jj = 0; jj < 8; ++jj) {
        int j = j0 + lc * 8 + jj;
        double v = 2.0 * acc2[ii][jj] - qa - sqA[(size_t)bg * NN + j];
        kk[((size_t)bl * NN + i) * MM + j] = pack_key64(v, j);
        if (mir) kk[((size_t)bl * NN + j) * MM + i] = pack_key64(v, i);
      }
    }
  }
}

// ------- top-20 per row from exact u64 keys; no fallback -------
__global__ __launch_bounds__(256) void k_topk(const u64* __restrict__ kk,
                                              int* __restrict__ idx, int b0) {
  int wave = threadIdx.x >> 6;
  int lane = threadIdx.x & 63;
  int bl = blockIdx.x;
  int row = blockIdx.y * 4 + wave;
  const u64* rp = kk + ((size_t)bl * NN + row) * MM;
  u64 s[16];
#pragma unroll
  for (int m = 0; m < 16; ++m) s[m] = rp[m * 64 + lane];
  int* op = idx + ((size_t)(b0 + bl) * NN + row) * KNN;
  topk20_u64(s, lane, op);
}

// --- fused per-point feature matmul (f64), both modes in one launch (4-wave,
// 1-D 256-thread block) ---
// mode 0: out0[b,j,o] = sum_c src0[b,j,c]*w[o,c]
// mode 1: out1[b,j,o] = sum_c src1[b,j,c]*(w[o,C+c]-w[o,c])
// MFMA path (if *flag) with probe-decoded D tables; VALU fallback otherwise.
__global__ __launch_bounds__(256) void k_featmm2(
    const double* __restrict__ src0, int ld0, int Np0,
    const double* __restrict__ src1, int ld1,
    const float* __restrict__ w, int CW,
    double* __restrict__ out0, double* __restrict__ out1, int C, int O,
    const int* __restrict__ rowt, const int* __restrict__ colt,
    const int* __restrict__ flag) {
  __shared__ double As[16][68];
  __shared__ double Ws[16][68];
  int nbo = O >> 6;
  int b = blockIdx.x;
  int mode = blockIdx.y >= nbo;
  int o0 = (blockIdx.y - (mode ? nbo : 0)) * 64;
  int j0 = blockIdx.z * 64;
  const double* src = mode ? src1 : src0;
  int lds_ = mode ? ld1 : ld0;
  int Np = mode ? NN : Np0;
  double* out = mode ? out1 : out0;
  int tid = threadIdx.x;
  const double* Sb = src + (size_t)b * Np * lds_;
  if (*flag) {
    int lane = tid & 63, wv = tid >> 6;
    int lm = lane & 15, lq = lane >> 4;
    f64x4 acc[4] = {};
    for (int c0 = 0; c0 < C; c0 += 16) {
      if (c0) __syncthreads();
      for (int r = 0; r < 4; ++r) {
        int li = tid + r * 256;
        int row = li >> 4, k = li & 15;
        int c = c0 + k;
        As[k][row] = (c < C) ? Sb[(size_t)(j0 + row) * lds_ + c] : 0.0;
        double wvv = 0.0;
        if (c < C) {
          const float* wr = w + (size_t)(o0 + row) * CW;
          wvv = (mode == 0) ? (double)wr[c] : ((double)wr[C + c] - (double)wr[c]);
        }
        Ws[k][row] = wvv;
      }
      __syncthreads();
#pragma unroll
      for (int kc = 0; kc < 4; ++kc) {
        double a = As[kc * 4 + lq][wv * 16 + lm];
#pragma unroll
        for (int t = 0; t < 4; ++t) {
          double bb = Ws[kc * 4 + lq][t * 16 + lm];
          acc[t] = __builtin_amdgcn_mfma_f64_16x16x4f64(a, bb, acc[t], 0, 0, 0);
        }
      }
    }
    int rta[4], cta[4];
#pragma unroll
    for (int r = 0; r < 4; ++r) {
      rta[r] = rowt[lane * 4 + r];
      cta[r] = colt[lane * 4 + r];
    }
#pragma unroll
    for (int t = 0; t < 4; ++t) {
#pragma unroll
      for (int r = 0; r < 4; ++r) {
        int j = j0 + wv * 16 + rta[r];
        int o = o0 + t * 16 + cta[r];
        out[((size_t)b * Np + j) * O + o] = acc[t][r];
      }
    }
  } else {
    int tx = tid & 15, ty = tid >> 4;
    double acc[4][4] = {};
    for (int c0 = 0; c0 < C; c0 += 16) {
      if (c0) __syncthreads();
      for (int r = 0; r < 4; ++r) {
        int li = tid + r * 256;
        int row = li >> 4, k = li & 15;
        int c = c0 + k;
        As[k][row] = (c < C) ? Sb[(size_t)(j0 + row) * lds_ + c] : 0.0;
        double wvv = 0.0;
        if (c < C) {
          const float* wr = w + (size_t)(o0 + row) * CW;
          wvv = (mode == 0) ? (double)wr[c] : ((double)wr[C + c] - (double)wr[c]);
        }
        Ws[k][row] = wvv;
      }
      __syncthreads();
#pragma unroll
      for (int k = 0; k < 16; ++k) {
        double a_[4], b_[4];
#pragma unroll
        for (int ii = 0; ii < 4; ++ii) a_[ii] = As[k][ty * 4 + ii];
#pragma unroll
        for (int jj = 0; jj < 4; ++jj) b_[jj] = Ws[k][tx * 4 + jj];
#pragma unroll
        for (int ii = 0; ii < 4; ++ii)
#pragma unroll
          for (int jj = 0; jj < 4; ++jj)
            acc[ii][jj] = fma(a_[ii], b_[jj], acc[ii][jj]);
      }
    }
    for (int ii = 0; ii < 4; ++ii) {
      int j = j0 + ty * 4 + ii;
      double* op = &out[((size_t)b * Np + j) * O + o0 + tx * 4];
      double2 v0, v1;
      v0.x = acc[ii][0];
      v0.y = acc[ii][1];
      v1.x = acc[ii][2];
      v1.y = acc[ii][3];
      *(double2*)op = v0;
      *(double2*)(op + 2) = v1;
    }
  }
}

// ---- layer-5 GEMM via bf16 MFMA: ONE WAVE per WG, 64x64 tile, K=512 unrolled ----
__global__ __launch_bounds__(64, 2) void k_gemm5_mfma(
    const __hip_bfloat16* __restrict__ cath, const __hip_bfloat16* __restrict__ w5h,
    float* __restrict__ out) {
  int b = blockIdx.x;
  int j0 = blockIdx.y * 64;
  int o0 = blockIdx.z * 64;
  int lane = threadIdx.x;
  int m = lane & 15;
  int quad = lane >> 4;
  const __hip_bfloat16* arow = cath + ((size_t)(b * NN + j0 + m)) * 512 + quad * 8;
  const __hip_bfloat16* brow = w5h + ((size_t)(o0 + m)) * 512 + quad * 8;
  f32x4 acc[4][4] = {};
#pragma unroll
  for (int c0 = 0; c0 < 512; c0 += 32) {
    bf16x8 a[4], bb[4];
#pragma unroll
    for (int s = 0; s < 4; ++s) {
      a[s] = *(const bf16x8*)(arow + (size_t)s * 16 * 512 + c0);
      bb[s] = *(const bf16x8*)(brow + (size_t)s * 16 * 512 + c0);
    }
#pragma unroll
    for (int si = 0; si < 4; ++si)
#pragma unroll
      for (int sj = 0; sj < 4; ++sj)
        acc[si][sj] =
            __builtin_amdgcn_mfma_f32_16x16x32_bf16(a[si], bb[sj], acc[si][sj], 0, 0, 0);
  }
  // D layout (verified): row = quad*4 + r, col = m, per 16x16 subtile
#pragma unroll
  for (int si = 0; si < 4; ++si) {
    float* ob = &out[((size_t)(b * NN + j0 + si * 16 + quad * 4)) * 512 + o0 + m];
#pragma unroll
    for (int sj = 0; sj < 4; ++sj)
#pragma unroll
      for (int r = 0; r < 4; ++r)
        ob[(size_t)r * 512 + sj * 16] = acc[si][sj][r];
  }
}

// ------- fused gather (f64): per (n,o) max_k y, accumulate BN stats -------
// Grid (O/64, NN/16, BB): b slowest -> per-XCD L2 residency of batch slices.
__global__ __launch_bounds__(256) void k_gather(
    const double* __restrict__ u, const double* __restrict__ t, const int* __restrict__ idx,
    double* __restrict__ stats, double* __restrict__ mx, int O, int srcNp) {
  __shared__ int lidx[16 * KNN];
  __shared__ double rs[256];
  __shared__ double rq[256];
  int b = blockIdx.z;
  int n0 = blockIdx.y * 16;
  int o0 = blockIdx.x * 64;
  int tid = threadIdx.x;
  int lane = tid & 63, nsl = tid >> 6;
  for (int w = tid; w < 16 * KNN; w += 256)
    lidx[w] = idx[((size_t)b * NN + n0) * KNN + w];
  __syncthreads();
  int oo = o0 + lane;
  double s1 = 0.0, s2 = 0.0;
  for (int ns = nsl; ns < 16; ns += 4) {
    size_t row = (size_t)b * NN + n0 + ns;
    double tv = t[row * O + oo];
    double mxv = -INFINITY;
    double a1 = 0.0, a2 = 0.0;
#pragma unroll
    for (int k = 0; k < KNN; ++k) {
      int j = lidx[ns * KNN + k];
      double yv = u[((size_t)b * srcNp + j) * O + oo] + tv;
      mxv = fmax(mxv, yv);
      a1 += yv;
      a2 = fma(yv, yv, a2);
    }
    mx[row * O + oo] = mxv;
    s1 += a1;
    s2 += a2;
  }
  rs[tid] = s1;
  rq[tid] = s2;
  __syncthreads();
  if (tid < 64) {
    s1 = rs[tid] + rs[tid + 64] + rs[tid + 128] + rs[tid + 192];
    s2 = rq[tid] + rq[tid + 64] + rq[tid + 128] + rq[tid + 192];
    atomicAdd(&stats[o0 + tid], s1);
    atomicAdd(&stats[O + o0 + tid], s2);
  }
}

// --- apply BN+lrelu to stored max (f64); BN fold computed per-WG in LDS ---
__global__ __launch_bounds__(256) void k_bnapply(
    const double* __restrict__ mx, const double* __restrict__ u, const double* __restrict__ t,
    const int* __restrict__ idx, const double* __restrict__ stats,
    const float* __restrict__ gamma, const float* __restrict__ beta, double cnt,
    double* __restrict__ catd, __hip_bfloat16* __restrict__ cath, int coff, int O,
    int srcNp) {
  __shared__ double scs[256];
  __shared__ double scc[256];
  int tid = threadIdx.x;
  if (tid < O) {
    double mean = stats[tid] / cnt;
    double var = stats[O + tid] / cnt - mean * mean;
    if (var < 0.0) var = 0.0;
    double rstd = 1.0 / sqrt(var + 1e-5);
    double s = (double)gamma[tid] * rstd;
    scs[tid] = s;
    scc[tid] = (double)beta[tid] - mean * s;
  }
  __syncthreads();
  int i = blockIdx.x * 256 + tid;
  int total = BB * NN * O;
  if (i >= total) return;
  int oo = i % O;
  int n = (i / O) % NN;
  int b = i / (O * NN);
  double s = scs[oo], c = scc[oo];
  double v;
  if (s >= 0.0) {
    v = mx[i];
  } else {  // monotone-decreasing transform needs min_k y (never hit with gamma=1)
    double tv = t[i];
    double mn = INFINITY;
    for (int k = 0; k < KNN; ++k) {
      int j = idx[((size_t)b * NN + n) * KNN + k];
      mn = fmin(mn, u[((size_t)b * srcNp + j) * O + oo] + tv);
    }
    v = mn;
  }
  double a = s * v + c;
  a = (a >= 0.0) ? a : 0.2 * a;
  size_t ci = ((size_t)b * NN + n) * 512 + coff + oo;
  cath[ci] = __float2bfloat16((float)a);
  if (coff < 256) catd[((size_t)b * NN + n) * 256 + coff + oo] = a;
}

// ------- layer 5 streaming stats over stored y5 (B,N,512) -------
__global__ __launch_bounds__(256) void k_stats512(
    const float* __restrict__ y5, double* __restrict__ stats) {
  int b = blockIdx.y;
  int n0 = blockIdx.x * 32;
  int tid = threadIdx.x;
  for (int part = 0; part < 2; ++part) {
    int oo = tid + part * 256;
    float a1 = 0.f, a2 = 0.f;
    for (int ns = 0; ns < 32; ++ns) {
      float v = y5[((size_t)b * NN + n0 + ns) * 512 + oo];
      a1 += v;
      a2 = fmaf(v, v, a2);
    }
    atomicAdd(&stats[oo], (double)a1);
    atomicAdd(&stats[512 + oo], (double)a2);
  }
}

// --- layer 5 finalize: BN fold in LDS, BN+lrelu on stored y5, transpose, store ---
__global__ __launch_bounds__(256) void k_final5b(
    const float* __restrict__ y5, const double* __restrict__ stats,
    const float* __restrict__ g5, const float* __restrict__ b5,
    float* __restrict__ out) {
  __shared__ float tile[64][65];
  __shared__ double scs[64];
  __shared__ double scc[64];
  int b = blockIdx.z;
  int n0 = blockIdx.x * 64;
  int o0 = blockIdx.y * 64;
  int tid = threadIdx.x;
  if (tid < 64) {
    int o = o0 + tid;
    double cnt = (double)(BB * NN);
    double mean = stats[o] / cnt;
    double var = stats[512 + o] / cnt - mean * mean;
    if (var < 0.0) var = 0.0;
    double rstd = 1.0 / sqrt(var + 1e-5);
    double s = (double)g5[o] * rstd;
    scs[tid] = s;
    scc[tid] = (double)b5[o] - mean * s;
  }
  __syncthreads();
  for (int r = 0; r < 16; ++r) {
    int li = tid + r * 256;
    int nl = li >> 6, ol = li & 63;
    float v = y5[((size_t)b * NN + n0 + nl) * 512 + o0 + ol];
    float a = (float)(scs[ol] * (double)v + scc[ol]);
    a = (a >= 0.f) ? a : NEG_SLOPE * a;
    tile[nl][ol] = a;
  }
  __syncthreads();
  for (int r = 0; r < 16; ++r) {
    int li = tid + r * 256;
    int ol = li >> 6, nl = li & 63;
    out[((size_t)b * 512 + o0 + ol) * NN + n0 + nl] = tile[nl][ol];
  }
}

// =====================================================================================
// r29: r28 REGRESSED (631->727): LDS-free channel-major gram quadrupled HBM fetch
// (8.3->37MB/dispatch) -- fine-grained fragment loads killed L2/L3 line reuse, and
// the latency LDS used to hide landed on the MFMA path (util 47->40%). Third failed
// gram restructure (r23, r28): r22's K8 double-buffer LDS body is the local optimum;
// frozen. REVERT to r27 (631us best) + ONE mechanism: batch-slowest grids for
// k_gram_u (z) and k_gram_sym (y) -- same per-XCD L2-residency lever that won r27's
// gather reorder. Kernel bodies byte-identical; only blockIdx mapping + launch dims.
extern "C" void kernel_launch(void* const* d_in, const int* in_sizes, int n_in,
                              void* d_out, int out_size, void* d_ws, size_t ws_size,
                              hipStream_t stream) {
  const float* x = (const float*)d_in[0];
  const float* y = (const float*)d_in[1];
  const float* w1 = (const float*)d_in[2];
  const float* w2 = (const float*)d_in[3];
  const float* w3 = (const float*)d_in[4];
  const float* w4 = (const float*)d_in[5];
  const float* w5 = (const float*)d_in[6];
  const float* g1 = (const float*)d_in[7];
  const float* b1 = (const float*)d_in[8];
  const float* g2 = (const float*)d_in[9];
  const float* b2 = (const float*)d_in[10];
  const float* g3 = (const float*)d_in[11];
  const float* b3 = (const float*)d_in[12];
  const float* g4 = (const float*)d_in[13];
  const float* b4 = (const float*)d_in[14];
  const float* g5 = (const float*)d_in[15];
  const float* b5 = (const float*)d_in[16];

  char* base = (char*)d_ws;
  size_t off = 0;
  auto alloc = [&](size_t bytes) -> char* {
    char* p = base + off;
    off += (bytes + 255) & ~(size_t)255;
    return p;
  };
  double* stAll = (double*)alloc(5 * 1024 * 8);  // 5 disjoint per-layer stat slots
  double* sq = (double*)alloc((size_t)BB * NN * 8);
  double* rnx = (double*)alloc((size_t)BB * NN * 8);
  double* rny = (double*)alloc((size_t)BB * MM * 8);
  int* idxb = (int*)alloc((size_t)BB * NN * KNN * 4);
  int* rowt = (int*)alloc(256 * 4);
  int* colt = (int*)alloc(256 * 4);
  int* pflag = (int*)alloc(256);
  double* xs3d = (double*)alloc((size_t)BB * NN * 3 * 8);
  double* ysd = (double*)alloc((size_t)BB * MM * 128 * 8);
  double* catd = (double*)alloc((size_t)BB * NN * 256 * 8);  // knn channels 0..255
  __hip_bfloat16* cath = (__hip_bfloat16*)alloc((size_t)BB * NN * 512 * 2);
  __hip_bfloat16* w5h = (__hip_bfloat16*)alloc((size_t)512 * 512 * 2);
  double* uu = (double*)alloc((size_t)BB * MM * 256 * 8);  // src term (max O=256)
  double* tt = (double*)alloc((size_t)BB * NN * 256 * 8);  // center term
  size_t kkBatchBytes = (size_t)NN * MM * 8;  // 8 MB per batch (u64 keys)
  size_t avail = (ws_size > off) ? (ws_size - off) : 0;
  int CB = (int)(avail / kkBatchBytes);
  if (CB < 1) CB = 1;
  if (CB > BB) CB = BB;
  u64* KK = (u64*)alloc((size_t)CB * kkBatchBytes);
  float* y5 = (float*)uu;             // layer-5 pre-BN (16MB), uu dead by then
  double* mx = (double*)d_out;        // max_k y (f64, <=16MB == out_size)
  float* outp = (float*)d_out;

  const double cntE = (double)BB * NN * KNN;

  // sym=1: triangular symmetric euclid gram (A==B); else general MODE-2 gram (L4)
  auto knn = [&](const double* A, int lda, const double* Bm, int ldb,
                 const double* sa, const double* sb, int C, int sym) {
    for (int b0 = 0; b0 < BB; b0 += CB) {
      int cb = (BB - b0 < CB) ? (BB - b0) : CB;
      if (sym) {
        k_gram_sym<<<dim3(136, cb), 64, 0, stream>>>(A, lda, sa, KK, C, b0, rowt, colt,
                                                     pflag);
      } else {
        dim3 g(MM / 64, NN / 64, cb);
        k_gram_u<2><<<g, 64, 0, stream>>>(A, lda, Bm, ldb, sa, sb, KK, C, b0, rowt,
                                          colt, pflag);
      }
      k_topk<<<dim3(cb, 256), 256, 0, stream>>>(KK, idxb, b0);
    }
  };

  auto edge_layer = [&](const double* ctr, int ldc, const double* src, int ldsrc,
                        int srcNp, const float* w, int CW, const float* g,
                        const float* bb, int C, int O, int coff, double* st) {
    k_featmm2<<<dim3(8, 2 * (O / 64), 16), 256, 0, stream>>>(
        src, ldsrc, srcNp, ctr, ldc, w, CW, uu, tt, C, O, rowt, colt, pflag);
    k_gather<<<dim3(O / 64, NN / 16, BB), 256, 0, stream>>>(uu, tt, idxb, st, mx, O,
                                                            srcNp);
    k_bnapply<<<(BB * NN * O + 255) / 256, 256, 0, stream>>>(
        mx, uu, tt, idxb, st, g, bb, cntE, catd, cath, coff, O, srcNp);
  };

  // ---- one upfront memset for ALL stat slots + probe + transposes + w5 bf16 ----
  hipMemsetAsync(stAll, 0, 5 * 1024 * 8, stream);
  k_probe_mfma<<<1, 64, 0, stream>>>(rowt, colt, pflag);
  k_transpose_d<<<96, 256, 0, stream>>>(x, xs3d, 3, NN);
  k_transpose_d<<<2048, 256, 0, stream>>>(y, ysd, 128, MM);
  k_cvt_bf16<<<1024, 256, 0, stream>>>(w5, w5h, 512 * 512);

  // ---- layer 1: C=3, O=64 (fused knn, no gram) ----
  k_rowsq<0><<<32, 256, 0, stream>>>(xs3d, 3, 3, sq);
  k_knn3<<<dim3(BB, 256), 256, 0, stream>>>(xs3d, sq, idxb);
  edge_layer(xs3d, 3, xs3d, 3, NN, w1, 6, g1, b1, 3, 64, 0, stAll);

  // ---- layer 2: x1 = catd[:,0:64], C=64, O=64 ----
  k_rowsq<0><<<32, 256, 0, stream>>>(catd, 256, 64, sq);
  knn(catd, 256, catd, 256, sq, sq, 64, 1);
  edge_layer(catd, 256, catd, 256, NN, w2, 128, g2, b2, 64, 64, 64, stAll + 1024);

  // ---- layer 3: x2 = catd[:,64:128], C=64, O=128 ----
  k_rowsq<0><<<32, 256, 0, stream>>>(catd + 64, 256, 64, sq);
  knn(catd + 64, 256, catd + 64, 256, sq, sq, 64, 1);
  edge_layer(catd + 64, 256, catd + 64, 256, NN, w3, 128, g3, b3, 64, 128, 128,
             stAll + 2048);

  // ---- layer 4 (IA): x3 = catd[:,128:256], src = y (cosine knn), C=128, O=256 ----
  k_rowsq<1><<<32, 256, 0, stream>>>(catd + 128, 256, 128, rnx);
  k_rowsq<1><<<32, 256, 0, stream>>>(ysd, 128, 128, rny);
  knn(catd + 128, 256, ysd, 128, rnx, rny, 128, 0);
  edge_layer(catd + 128, 256, ysd, 128, MM, w4, 256, g4, b4, 128, 256, 256,
             stAll + 3072);

  // ---- layer 5: bf16-MFMA GEMM -> y5 (aliases uu), BN over (B,N), lrelu, transpose ----
  double* st5 = stAll + 4096;
  k_gemm5_mfma<<<dim3(8, 16, 8), 64, 0, stream>>>(cath, w5h, y5);
  k_stats512<<<dim3(32, 8), 256, 0, stream>>>(y5, st5);
  k_final5b<<<dim3(16, 8, 8), 256, 0, stream>>>(y5, st5, g5, b5, outp);
}

// Round 17
// 585.927 us; speedup vs baseline: 1.2413x; 1.0779x over previous
//
#include <hip/hip_runtime.h>
#include <hip/hip_bf16.h>

#define KNN 20
#define NEG_SLOPE 0.2f

constexpr int BB = 8;
constexpr int NN = 1024;
constexpr int MM = 1024;

typedef short bf16x8 __attribute__((ext_vector_type(8)));
typedef float f32x4 __attribute__((ext_vector_type(4)));
typedef double f64x4 __attribute__((ext_vector_type(4)));
typedef unsigned long long u64;

// ================= top-20 selection via exact u64 keys =================
// Monotone f64->u64 map, low 10 bits replaced by inverted column index.
// Key order == f64 descending order with tie -> lower idx (jax top_k semantics).
__device__ __forceinline__ u64 pack_key64(double d, int j) {
  u64 u = (u64)__double_as_longlong(d);
  u = (u & 0x8000000000000000ULL) ? ~u : (u | 0x8000000000000000ULL);
  return (u & ~(u64)1023) | (u64)(1023 - j);
}

// Per-wave top-20: each lane holds 16 keys; Batcher odd-even mergesort (desc),
// then 20 extraction rounds (wave-max + winner-lane shift). Exact, no fallback.
__device__ __forceinline__ void topk20_u64(u64 (&s)[16], int lane, int* op) {
#pragma unroll
  for (int p = 1; p < 16; p <<= 1) {
#pragma unroll
    for (int k = p; k >= 1; k >>= 1) {
#pragma unroll
      for (int j = k % p; j + k < 16; j += 2 * k) {
#pragma unroll
        for (int i = 0; i < k; ++i) {
          int a = j + i, b = j + i + k;
          if (b < 16 && (a / (2 * p)) == (b / (2 * p))) {
            u64 hi = s[a] > s[b] ? s[a] : s[b];
            u64 lo = s[a] > s[b] ? s[b] : s[a];
            s[a] = hi;
            s[b] = lo;
          }
        }
      }
    }
  }
#pragma unroll
  for (int r = 0; r < KNN; ++r) {
    u64 win = s[0];
#pragma unroll
    for (int off = 32; off > 0; off >>= 1) {
      u64 o = __shfl_xor(win, off, 64);
      win = o > win ? o : win;
    }
    if (lane == 0) op[r] = 1023 - (int)(win & (u64)1023);
    if (s[0] == win) {
#pragma unroll
      for (int i = 0; i < 15; ++i) s[i] = s[i + 1];
      s[15] = 0ULL;
    }
  }
}

// ======== f64 MFMA layout self-probe + decode, fused (one wave, ~3us) ========
__global__ void k_probe_mfma(int* __restrict__ rowt, int* __restrict__ colt,
                             int* __restrict__ flag) {
  __shared__ int cnt[256];
  __shared__ int oksh;
  int tid = threadIdx.x;  // 64 threads
  if (tid == 0) oksh = 1;
  for (int e = tid; e < 256; e += 64) cnt[e] = 0;
  __syncthreads();
  int lane = tid & 63;
  f64x4 z = {0.0, 0.0, 0.0, 0.0};
  double ai = (double)(lane & 15);
  double p3 = 1.0, p5 = 1.0;
  int kq = lane >> 4;
  for (int t = 0; t < kq; ++t) { p3 *= 3.0; p5 *= 5.0; }
  f64x4 d1 = __builtin_amdgcn_mfma_f64_16x16x4f64(ai, 1.0, z, 0, 0, 0);
  f64x4 d2 = __builtin_amdgcn_mfma_f64_16x16x4f64(1.0, ai, z, 0, 0, 0);
  f64x4 d3 = __builtin_amdgcn_mfma_f64_16x16x4f64(p3, p5, z, 0, 0, 0);
  bool ok = true;
  int ri[4], ci[4];
#pragma unroll
  for (int r = 0; r < 4; ++r) {
    double va = d1[r], vb = d2[r], vp = d3[r];
    int i = (int)(va * 0.25);
    int j = (int)(vb * 0.25);
    bool e_ok = (i >= 0) && (i < 16) && (j >= 0) && (j < 16) &&
                (va == 4.0 * (double)i) && (vb == 4.0 * (double)j) && (vp == 3616.0);
    if (e_ok) {
      atomicAdd(&cnt[i * 16 + j], 1);
    } else {
      ok = false;
      i = 0;
      j = 0;
    }
    ri[r] = i;
    ci[r] = j;
  }
  if (!ok) atomicExch(&oksh, 0);
  __syncthreads();
  bool bij = true;
  for (int e = tid; e < 256; e += 64)
    if (cnt[e] != 1) bij = false;
  if (!bij) atomicExch(&oksh, 0);
  __syncthreads();
#pragma unroll
  for (int r = 0; r < 4; ++r) {
    rowt[lane * 4 + r] = ri[r];
    colt[lane * 4 + r] = ci[r];
  }
  if (tid == 0) *flag = oksh;
}

// ---------------- transpose f32 -> f64: (B,C,Np) -> (B,Np,C) ----------------
__global__ __launch_bounds__(256) void k_transpose_d(
    const float* __restrict__ in, double* __restrict__ out, int C, int Np) {
  int total = BB * C * Np;
  for (int t = blockIdx.x * 256 + threadIdx.x; t < total; t += gridDim.x * 256) {
    int c = t % C;
    int n = (t / C) % Np;
    int b = t / (C * Np);
    out[t] = (double)in[((size_t)b * C + c) * Np + n];
  }
}

// ---------------- f32 -> bf16 convert ----------------
__global__ __launch_bounds__(256) void k_cvt_bf16(
    const float* __restrict__ in, __hip_bfloat16* __restrict__ out, int n) {
  int i = blockIdx.x * 256 + threadIdx.x;
  if (i < n) out[i] = __float2bfloat16(in[i]);
}

// ------- per-point squared norm (RECIP=0) or reciprocal norm (RECIP=1), f64 -------
template <int RECIP>
__global__ __launch_bounds__(256) void k_rowsq(
    const double* __restrict__ A, int ld, int C, double* __restrict__ sq) {
  int p = blockIdx.x * 256 + threadIdx.x;
  if (p >= BB * NN) return;
  const double* row = A + (size_t)p * ld;
  double s = 0.0;
  for (int c = 0; c < C; ++c) { double v = row[c]; s += v * v; }
  if (RECIP) {
    sq[p] = 1.0 / fmax(sqrt(s), 1e-12);
  } else {
    sq[p] = s;
  }
}

// ---- fused L1 knn (C=3): all points in LDS (f64), u64-key topk (exact) ----
__global__ __launch_bounds__(256) void k_knn3(
    const double* __restrict__ xs3, const double* __restrict__ sq, int* __restrict__ idx) {
  __shared__ double P[NN * 3];
  int b = blockIdx.x;
  const double* Xb = xs3 + (size_t)b * NN * 3;
  int tid = threadIdx.x;
  for (int t = tid; t < NN * 3; t += 256) P[t] = Xb[t];
  __syncthreads();
  int wave = tid >> 6, lane = tid & 63;
  int i = blockIdx.y * 4 + wave;
  double xi = P[i * 3], yi = P[i * 3 + 1], zi = P[i * 3 + 2];
  double sqi = sq[b * NN + i];
  u64 s[16];
#pragma unroll
  for (int m = 0; m < 16; ++m) {
    int j = m * 64 + lane;
    double d = fma(xi, P[j * 3], 0.0);
    d = fma(yi, P[j * 3 + 1], d);
    d = fma(zi, P[j * 3 + 2], d);
    s[m] = pack_key64(2.0 * d - sqi - sq[b * NN + j], j);
  }
  int* op = idx + ((size_t)b * NN + i) * KNN;
  topk20_u64(s, lane, op);
}

// ---- gram (r22-verified body): ONE WAVE per WG, 64x64 tile, K-block 8,
// barrier-free in-wave DOUBLE buffer. Probe-decoded D tables; VALU fallback.
// MODE 1: D=2*dot-sqA_i-sqB_j ; MODE 2: dot*rnA*rnB
template <int MODE>
__global__ __launch_bounds__(64, 2) void k_gram_u(
    const double* __restrict__ A, int lda, const double* __restrict__ Bm, int ldb,
    const double* __restrict__ sqA, const double* __restrict__ sqB,
    u64* __restrict__ kk, int C, int b0, const int* __restrict__ rowt,
    const int* __restrict__ colt, const int* __restrict__ flag) {
  __shared__ double As[2][8][69];
  __shared__ double Bs[2][8][69];
  int bl = blockIdx.z;
  int bg = b0 + bl;
  int j0 = blockIdx.x * 64;
  int i0 = blockIdx.y * 64;
  const double* Ab = A + (size_t)bg * NN * lda;
  const double* Bb = Bm + (size_t)bg * MM * ldb;
  int lane = threadIdx.x;
  if (*flag) {
    int lm = lane & 15, lq = lane >> 4;
    int k8 = lane & 7, r8 = lane >> 3;  // staging coords: k fixed, rows r8+8r
    const double* pa = Ab + (size_t)(i0 + r8) * lda + k8;
    const double* pb = Bb + (size_t)(j0 + r8) * ldb + k8;
    f64x4 acc[4][4] = {};
    double ra[8], rb[8];
    // prologue: stage K-block 0 into buffer 0
#pragma unroll
    for (int r = 0; r < 8; ++r) {
      ra[r] = pa[(size_t)(8 * r) * lda];
      rb[r] = pb[(size_t)(8 * r) * ldb];
    }
#pragma unroll
    for (int r = 0; r < 8; ++r) {
      As[0][k8][r8 + 8 * r] = ra[r];
      Bs[0][k8][r8 + 8 * r] = rb[r];
    }
    int nblk = C >> 3;
    for (int cb = 0; cb < nblk; ++cb) {
      int buf = cb & 1;
      bool pf = (cb + 1 < nblk);
      if (pf) {  // issue next block's loads; vmcnt wait lands after the MFMAs
        int c0 = (cb + 1) << 3;
#pragma unroll
        for (int r = 0; r < 8; ++r) {
          ra[r] = pa[(size_t)(8 * r) * lda + c0];
          rb[r] = pb[(size_t)(8 * r) * ldb + c0];
        }
      }
#pragma unroll
      for (int kc = 0; kc < 2; ++kc) {
        double a_[4], b_[4];
#pragma unroll
        for (int s = 0; s < 4; ++s) {
          a_[s] = As[buf][kc * 4 + lq][s * 16 + lm];
          b_[s] = Bs[buf][kc * 4 + lq][s * 16 + lm];
        }
#pragma unroll
        for (int si = 0; si < 4; ++si)
#pragma unroll
          for (int sj = 0; sj < 4; ++sj)
            acc[si][sj] = __builtin_amdgcn_mfma_f64_16x16x4f64(a_[si], b_[sj],
                                                               acc[si][sj], 0, 0, 0);
      }
      if (pf) {  // fill the other buffer (per-wave DS in-order: no barrier)
        int nb = buf ^ 1;
#pragma unroll
        for (int r = 0; r < 8; ++r) {
          As[nb][k8][r8 + 8 * r] = ra[r];
          Bs[nb][k8][r8 + 8 * r] = rb[r];
        }
      }
    }
    int rta[4], cta[4];
#pragma unroll
    for (int r = 0; r < 4; ++r) {
      rta[r] = rowt[lane * 4 + r];
      cta[r] = colt[lane * 4 + r];
    }
#pragma unroll
    for (int si = 0; si < 4; ++si) {
#pragma unroll
      for (int sj = 0; sj < 4; ++sj) {
#pragma unroll
        for (int r = 0; r < 4; ++r) {
          int i = i0 + si * 16 + rta[r];
          int j = j0 + sj * 16 + cta[r];
          double v = acc[si][sj][r];
          if (MODE == 1)
            v = 2.0 * v - sqA[(size_t)bg * NN + i] - sqB[(size_t)bg * MM + j];
          if (MODE == 2) v = v * sqA[(size_t)bg * NN + i] * sqB[(size_t)bg * MM + j];
          kk[((size_t)bl * NN + i) * MM + j] = pack_key64(v, j);
        }
      }
    }
  } else {
    int lr = lane >> 3, lc = lane & 7;  // 8x8 lane grid, 8x8 outputs each
    double acc2[8][8] = {};
    for (int c0 = 0; c0 < C; c0 += 8) {
      if (c0) __syncthreads();
      for (int r = 0; r < 8; ++r) {
        int li = lane + r * 64;
        int row = li >> 3, k = li & 7;
        As[0][k][row] = Ab[(size_t)(i0 + row) * lda + c0 + k];
        Bs[0][k][row] = Bb[(size_t)(j0 + row) * ldb + c0 + k];
      }
      __syncthreads();
#pragma unroll
      for (int k = 0; k < 8; ++k) {
        double a_[8], b_[8];
#pragma unroll
        for (int t = 0; t < 8; ++t) {
          a_[t] = As[0][k][lr * 8 + t];
          b_[t] = Bs[0][k][lc * 8 + t];
        }
#pragma unroll
        for (int ii = 0; ii < 8; ++ii)
#pragma unroll
          for (int jj = 0; jj < 8; ++jj)
            acc2[ii][jj] = fma(a_[ii], b_[jj], acc2[ii][jj]);
      }
    }
    for (int ii = 0; ii < 8; ++ii) {
      int i = i0 + lr * 8 + ii;
      double qa = sqA[(size_t)bg * NN + i];
      for (int jj = 0; jj < 8; ++jj) {
        int j = j0 + lc * 8 + jj;
        double v = acc2[ii][jj];
        if (MODE == 1) v = 2.0 * v - qa - sqB[(size_t)bg * MM + j];
        if (MODE == 2) v = v * qa * sqB[(size_t)bg * MM + j];
        kk[((size_t)bl * NN + i) * MM + j] = pack_key64(v, j);
      }
    }
  }
}

// ---- symmetric euclid gram (A==B, layers 2/3): triangular 136-block grid,
// r22-verified inner loop; off-diagonal tiles also write mirrored key.
__global__ __launch_bounds__(64, 2) void k_gram_sym(
    const double* __restrict__ A, int lda, const double* __restrict__ sqA,
    u64* __restrict__ kk, int C, int b0, const int* __restrict__ rowt,
    const int* __restrict__ colt, const int* __restrict__ flag) {
  __shared__ double As[2][8][69];
  __shared__ double Bs[2][8][69];
  int p = blockIdx.x;  // 0..135 triangular pair index (fastest)
  int bl = blockIdx.y;
  int bg = b0 + bl;
  int r = (int)((sqrtf(8.f * p + 1.f) - 1.f) * 0.5f);
  while ((r + 1) * (r + 2) / 2 <= p) ++r;
  while (r * (r + 1) / 2 > p) --r;
  int cc = p - r * (r + 1) / 2;
  int i0 = r * 64, j0 = cc * 64;
  const double* Ab = A + (size_t)bg * NN * lda;
  int lane = threadIdx.x;
  if (*flag) {
    int lm = lane & 15, lq = lane >> 4;
    int k8 = lane & 7, r8 = lane >> 3;
    const double* pa = Ab + (size_t)(i0 + r8) * lda + k8;
    const double* pb = Ab + (size_t)(j0 + r8) * lda + k8;
    f64x4 acc[4][4] = {};
    double ra[8], rb[8];
#pragma unroll
    for (int r_ = 0; r_ < 8; ++r_) {
      ra[r_] = pa[(size_t)(8 * r_) * lda];
      rb[r_] = pb[(size_t)(8 * r_) * lda];
    }
#pragma unroll
    for (int r_ = 0; r_ < 8; ++r_) {
      As[0][k8][r8 + 8 * r_] = ra[r_];
      Bs[0][k8][r8 + 8 * r_] = rb[r_];
    }
    int nblk = C >> 3;
    for (int cb = 0; cb < nblk; ++cb) {
      int buf = cb & 1;
      bool pf = (cb + 1 < nblk);
      if (pf) {
        int c0 = (cb + 1) << 3;
#pragma unroll
        for (int r_ = 0; r_ < 8; ++r_) {
          ra[r_] = pa[(size_t)(8 * r_) * lda + c0];
          rb[r_] = pb[(size_t)(8 * r_) * lda + c0];
        }
      }
#pragma unroll
      for (int kc = 0; kc < 2; ++kc) {
        double a_[4], b_[4];
#pragma unroll
        for (int s = 0; s < 4; ++s) {
          a_[s] = As[buf][kc * 4 + lq][s * 16 + lm];
          b_[s] = Bs[buf][kc * 4 + lq][s * 16 + lm];
        }
#pragma unroll
        for (int si = 0; si < 4; ++si)
#pragma unroll
          for (int sj = 0; sj < 4; ++sj)
            acc[si][sj] = __builtin_amdgcn_mfma_f64_16x16x4f64(a_[si], b_[sj],
                                                               acc[si][sj], 0, 0, 0);
      }
      if (pf) {
        int nb = buf ^ 1;
#pragma unroll
        for (int r_ = 0; r_ < 8; ++r_) {
          As[nb][k8][r8 + 8 * r_] = ra[r_];
          Bs[nb][k8][r8 + 8 * r_] = rb[r_];
        }
      }
    }
    int rta[4], cta[4];
#pragma unroll
    for (int r_ = 0; r_ < 4; ++r_) {
      rta[r_] = rowt[lane * 4 + r_];
      cta[r_] = colt[lane * 4 + r_];
    }
    bool mir = (i0 != j0);
#pragma unroll
    for (int si = 0; si < 4; ++si) {
#pragma unroll
      for (int sj = 0; sj < 4; ++sj) {
#pragma unroll
        for (int r_ = 0; r_ < 4; ++r_) {
          int i = i0 + si * 16 + rta[r_];
          int j = j0 + sj * 16 + cta[r_];
          double v = 2.0 * acc[si][sj][r_] - sqA[(size_t)bg * NN + i] -
                     sqA[(size_t)bg * NN + j];
          kk[((size_t)bl * NN + i) * MM + j] = pack_key64(v, j);
          if (mir) kk[((size_t)bl * NN + j) * MM + i] = pack_key64(v, i);
        }
      }
    }
  } else {
    int lr = lane >> 3, lc = lane & 7;
    double acc2[8][8] = {};
    for (int c0 = 0; c0 < C; c0 += 8) {
      if (c0) __syncthreads();
      for (int r_ = 0; r_ < 8; ++r_) {
        int li = lane + r_ * 64;
        int row = li >> 3, k = li & 7;
        As[0][k][row] = Ab[(size_t)(i0 + row) * lda + c0 + k];
        Bs[0][k][row] = Ab[(size_t)(j0 + row) * lda + c0 + k];
      }
      __syncthreads();
#pragma unroll
      for (int k = 0; k < 8; ++k) {
        double a_[8], b_[8];
#pragma unroll
        for (int t = 0; t < 8; ++t) {
          a_[t] = As[0][k][lr * 8 + t];
          b_[t] = Bs[0][k][lc * 8 + t];
        }
#pragma unroll
        for (int ii = 0; ii < 8; ++ii)
#pragma unroll
          for (int jj = 0; jj < 8; ++jj)
            acc2[ii][jj] = fma(a_[ii], b_[jj], acc2[ii][jj]);
      }
    }
    bool mir = (i0 != j0);
    for (int ii = 0; ii < 8; ++ii) {
      int i = i0 + lr * 8 + ii;
      double qa = sqA[(size_t)bg * NN + i];
      for (int jj = 0; jj < 8; ++jj) {
        int j = j0 + lc * 8 + jj;
        double v = 2.0 * acc2[ii][jj] - qa - sqA[(size_t)bg * NN + j];
        kk[((size_t)bl * NN + i) * MM + j] = pack_key64(v, j);
        if (mir) kk[((size_t)bl * NN + j) * MM + i] = pack_key64(v, i);
      }
    }
  }
}

// ------- top-20 per row from exact u64 keys; no fallback -------
__global__ __launch_bounds__(256) void k_topk(const u64* __restrict__ kk,
                                              int* __restrict__ idx, int b0) {
  int wave = threadIdx.x >> 6;
  int lane = threadIdx.x & 63;
  int bl = blockIdx.x;
  int row = blockIdx.y * 4 + wave;
  const u64* rp = kk + ((size_t)bl * NN + row) * MM;
  u64 s[16];
#pragma unroll
  for (int m = 0; m < 16; ++m) s[m] = rp[m * 64 + lane];
  int* op = idx + ((size_t)(b0 + bl) * NN + row) * KNN;
  topk20_u64(s, lane, op);
}

// --- fused per-point feature matmul (f64), both modes in one launch (4-wave,
// 1-D 256-thread block) ---
__global__ __launch_bounds__(256) void k_featmm2(
    const double* __restrict__ src0, int ld0, int Np0,
    const double* __restrict__ src1, int ld1,
    const float* __restrict__ w, int CW,
    double* __restrict__ out0, double* __restrict__ out1, int C, int O,
    const int* __restrict__ rowt, const int* __restrict__ colt,
    const int* __restrict__ flag) {
  __shared__ double As[16][68];
  __shared__ double Ws[16][68];
  int nbo = O >> 6;
  int b = blockIdx.x;
  int mode = blockIdx.y >= nbo;
  int o0 = (blockIdx.y - (mode ? nbo : 0)) * 64;
  int j0 = blockIdx.z * 64;
  const double* src = mode ? src1 : src0;
  int lds_ = mode ? ld1 : ld0;
  int Np = mode ? NN : Np0;
  double* out = mode ? out1 : out0;
  int tid = threadIdx.x;
  const double* Sb = src + (size_t)b * Np * lds_;
  if (*flag) {
    int lane = tid & 63, wv = tid >> 6;
    int lm = lane & 15, lq = lane >> 4;
    f64x4 acc[4] = {};
    for (int c0 = 0; c0 < C; c0 += 16) {
      if (c0) __syncthreads();
      for (int r = 0; r < 4; ++r) {
        int li = tid + r * 256;
        int row = li >> 4, k = li & 15;
        int c = c0 + k;
        As[k][row] = (c < C) ? Sb[(size_t)(j0 + row) * lds_ + c] : 0.0;
        double wvv = 0.0;
        if (c < C) {
          const float* wr = w + (size_t)(o0 + row) * CW;
          wvv = (mode == 0) ? (double)wr[c] : ((double)wr[C + c] - (double)wr[c]);
        }
        Ws[k][row] = wvv;
      }
      __syncthreads();
#pragma unroll
      for (int kc = 0; kc < 4; ++kc) {
        double a = As[kc * 4 + lq][wv * 16 + lm];
#pragma unroll
        for (int t = 0; t < 4; ++t) {
          double bb = Ws[kc * 4 + lq][t * 16 + lm];
          acc[t] = __builtin_amdgcn_mfma_f64_16x16x4f64(a, bb, acc[t], 0, 0, 0);
        }
      }
    }
    int rta[4], cta[4];
#pragma unroll
    for (int r = 0; r < 4; ++r) {
      rta[r] = rowt[lane * 4 + r];
      cta[r] = colt[lane * 4 + r];
    }
#pragma unroll
    for (int t = 0; t < 4; ++t) {
#pragma unroll
      for (int r = 0; r < 4; ++r) {
        int j = j0 + wv * 16 + rta[r];
        int o = o0 + t * 16 + cta[r];
        out[((size_t)b * Np + j) * O + o] = acc[t][r];
      }
    }
  } else {
    int tx = tid & 15, ty = tid >> 4;
    double acc[4][4] = {};
    for (int c0 = 0; c0 < C; c0 += 16) {
      if (c0) __syncthreads();
      for (int r = 0; r < 4; ++r) {
        int li = tid + r * 256;
        int row = li >> 4, k = li & 15;
        int c = c0 + k;
        As[k][row] = (c < C) ? Sb[(size_t)(j0 + row) * lds_ + c] : 0.0;
        double wvv = 0.0;
        if (c < C) {
          const float* wr = w + (size_t)(o0 + row) * CW;
          wvv = (mode == 0) ? (double)wr[c] : ((double)wr[C + c] - (double)wr[c]);
        }
        Ws[k][row] = wvv;
      }
      __syncthreads();
#pragma unroll
      for (int k = 0; k < 16; ++k) {
        double a_[4], b_[4];
#pragma unroll
        for (int ii = 0; ii < 4; ++ii) a_[ii] = As[k][ty * 4 + ii];
#pragma unroll
        for (int jj = 0; jj < 4; ++jj) b_[jj] = Ws[k][tx * 4 + jj];
#pragma unroll
        for (int ii = 0; ii < 4; ++ii)
#pragma unroll
          for (int jj = 0; jj < 4; ++jj)
            acc[ii][jj] = fma(a_[ii], b_[jj], acc[ii][jj]);
      }
    }
    for (int ii = 0; ii < 4; ++ii) {
      int j = j0 + ty * 4 + ii;
      double* op = &out[((size_t)b * Np + j) * O + o0 + tx * 4];
      double2 v0, v1;
      v0.x = acc[ii][0];
      v0.y = acc[ii][1];
      v1.x = acc[ii][2];
      v1.y = acc[ii][3];
      *(double2*)op = v0;
      *(double2*)(op + 2) = v1;
    }
  }
}

// ---- layer-5 GEMM via bf16 MFMA: ONE WAVE per WG, 64x64 tile, K=512 unrolled.
// NEW: BN stats fused into epilogue -- per-o column sums reduced across quads
// via shfl_xor(16/32), then 2 atomicAdds per (o,sj) from quad-0 lanes. Replaces
// the separate k_stats512 pass (16MB y5 re-read + launch).
__global__ __launch_bounds__(64, 2) void k_gemm5_mfma(
    const __hip_bfloat16* __restrict__ cath, const __hip_bfloat16* __restrict__ w5h,
    float* __restrict__ out, double* __restrict__ stats) {
  int b = blockIdx.x;
  int j0 = blockIdx.y * 64;
  int o0 = blockIdx.z * 64;
  int lane = threadIdx.x;
  int m = lane & 15;
  int quad = lane >> 4;
  const __hip_bfloat16* arow = cath + ((size_t)(b * NN + j0 + m)) * 512 + quad * 8;
  const __hip_bfloat16* brow = w5h + ((size_t)(o0 + m)) * 512 + quad * 8;
  f32x4 acc[4][4] = {};
#pragma unroll
  for (int c0 = 0; c0 < 512; c0 += 32) {
    bf16x8 a[4], bb[4];
#pragma unroll
    for (int s = 0; s < 4; ++s) {
      a[s] = *(const bf16x8*)(arow + (size_t)s * 16 * 512 + c0);
      bb[s] = *(const bf16x8*)(brow + (size_t)s * 16 * 512 + c0);
    }
#pragma unroll
    for (int si = 0; si < 4; ++si)
#pragma unroll
      for (int sj = 0; sj < 4; ++sj)
        acc[si][sj] =
            __builtin_amdgcn_mfma_f32_16x16x32_bf16(a[si], bb[sj], acc[si][sj], 0, 0, 0);
  }
  // D layout (verified): row = quad*4 + r, col = m, per 16x16 subtile
#pragma unroll
  for (int si = 0; si < 4; ++si) {
    float* ob = &out[((size_t)(b * NN + j0 + si * 16 + quad * 4)) * 512 + o0 + m];
#pragma unroll
    for (int sj = 0; sj < 4; ++sj)
#pragma unroll
      for (int r = 0; r < 4; ++r)
        ob[(size_t)r * 512 + sj * 16] = acc[si][sj][r];
  }
  // fused BN stats: per-lane column partials over this wave's 64 j's
#pragma unroll
  for (int sj = 0; sj < 4; ++sj) {
    float s1 = 0.f, s2 = 0.f;
#pragma unroll
    for (int si = 0; si < 4; ++si)
#pragma unroll
      for (int r = 0; r < 4; ++r) {
        float v = acc[si][sj][r];
        s1 += v;
        s2 = fmaf(v, v, s2);
      }
    s1 += __shfl_xor(s1, 16, 64);
    s1 += __shfl_xor(s1, 32, 64);
    s2 += __shfl_xor(s2, 16, 64);
    s2 += __shfl_xor(s2, 32, 64);
    if (quad == 0) {
      int o = o0 + sj * 16 + m;
      atomicAdd(&stats[o], (double)s1);
      atomicAdd(&stats[512 + o], (double)s2);
    }
  }
}

// ------- fused gather (f64): per (n,o) max_k y, accumulate BN stats -------
// Grid (O/64, NN/16, BB): b slowest -> per-XCD L2 residency of batch slices.
__global__ __launch_bounds__(256) void k_gather(
    const double* __restrict__ u, const double* __restrict__ t, const int* __restrict__ idx,
    double* __restrict__ stats, double* __restrict__ mx, int O, int srcNp) {
  __shared__ int lidx[16 * KNN];
  __shared__ double rs[256];
  __shared__ double rq[256];
  int b = blockIdx.z;
  int n0 = blockIdx.y * 16;
  int o0 = blockIdx.x * 64;
  int tid = threadIdx.x;
  int lane = tid & 63, nsl = tid >> 6;
  for (int w = tid; w < 16 * KNN; w += 256)
    lidx[w] = idx[((size_t)b * NN + n0) * KNN + w];
  __syncthreads();
  int oo = o0 + lane;
  double s1 = 0.0, s2 = 0.0;
  for (int ns = nsl; ns < 16; ns += 4) {
    size_t row = (size_t)b * NN + n0 + ns;
    double tv = t[row * O + oo];
    double mxv = -INFINITY;
    double a1 = 0.0, a2 = 0.0;
#pragma unroll
    for (int k = 0; k < KNN; ++k) {
      int j = lidx[ns * KNN + k];
      double yv = u[((size_t)b * srcNp + j) * O + oo] + tv;
      mxv = fmax(mxv, yv);
      a1 += yv;
      a2 = fma(yv, yv, a2);
    }
    mx[row * O + oo] = mxv;
    s1 += a1;
    s2 += a2;
  }
  rs[tid] = s1;
  rq[tid] = s2;
  __syncthreads();
  if (tid < 64) {
    s1 = rs[tid] + rs[tid + 64] + rs[tid + 128] + rs[tid + 192];
    s2 = rq[tid] + rq[tid + 64] + rq[tid + 128] + rq[tid + 192];
    atomicAdd(&stats[o0 + tid], s1);
    atomicAdd(&stats[O + o0 + tid], s2);
  }
}

// --- apply BN+lrelu to stored max (f64); BN fold in LDS. NRM: fused next-layer
// norm -- 0: none; 1: Sum a^2 -> nrm[p] (O==64, one wave = one point);
// 2: 1/sqrt(Sum a^2) -> nrm[p] (O==128, two waves combine via LDS).
template <int NRM>
__global__ __launch_bounds__(256) void k_bnapply(
    const double* __restrict__ mx, const double* __restrict__ u, const double* __restrict__ t,
    const int* __restrict__ idx, const double* __restrict__ stats,
    const float* __restrict__ gamma, const float* __restrict__ beta, double cnt,
    double* __restrict__ catd, __hip_bfloat16* __restrict__ cath, int coff, int O,
    int srcNp, double* __restrict__ nrm) {
  __shared__ double scs[256];
  __shared__ double scc[256];
  __shared__ double part[4];
  int tid = threadIdx.x;
  if (tid < O) {
    double mean = stats[tid] / cnt;
    double var = stats[O + tid] / cnt - mean * mean;
    if (var < 0.0) var = 0.0;
    double rstd = 1.0 / sqrt(var + 1e-5);
    double s = (double)gamma[tid] * rstd;
    scs[tid] = s;
    scc[tid] = (double)beta[tid] - mean * s;
  }
  __syncthreads();
  int i = blockIdx.x * 256 + tid;
  int oo = i % O;
  int n = (i / O) % NN;
  int b = i / (O * NN);
  double s = scs[oo], c = scc[oo];
  double v;
  if (s >= 0.0) {
    v = mx[i];
  } else {  // monotone-decreasing transform needs min_k y (never hit with gamma=1)
    double tv = t[i];
    double mn = INFINITY;
    for (int k = 0; k < KNN; ++k) {
      int j = idx[((size_t)b * NN + n) * KNN + k];
      mn = fmin(mn, u[((size_t)b * srcNp + j) * O + oo] + tv);
    }
    v = mn;
  }
  double a = s * v + c;
  a = (a >= 0.0) ? a : 0.2 * a;
  size_t ci = ((size_t)b * NN + n) * 512 + coff + oo;
  cath[ci] = __float2bfloat16((float)a);
  if (coff < 256) catd[((size_t)b * NN + n) * 256 + coff + oo] = a;
  if (NRM > 0) {
    double q = a * a;
#pragma unroll
    for (int off = 32; off > 0; off >>= 1) q += __shfl_xor(q, off, 64);
    if (NRM == 1) {  // O==64: one wave == one point
      if ((tid & 63) == 0) nrm[i >> 6] = q;
    } else {  // NRM==2, O==128: two waves per point
      int wv = tid >> 6;
      if ((tid & 63) == 0) part[wv] = q;
      __syncthreads();
      if ((tid & 127) == 0) {
        double tot = part[wv] + part[wv + 1];
        nrm[i >> 7] = 1.0 / fmax(sqrt(tot), 1e-12);
      }
    }
  }
}

// --- layer 5 finalize: BN fold in LDS, BN+lrelu on stored y5, transpose, store ---
__global__ __launch_bounds__(256) void k_final5b(
    const float* __restrict__ y5, const double* __restrict__ stats,
    const float* __restrict__ g5, const float* __restrict__ b5,
    float* __restrict__ out) {
  __shared__ float tile[64][65];
  __shared__ double scs[64];
  __shared__ double scc[64];
  int b = blockIdx.z;
  int n0 = blockIdx.x * 64;
  int o0 = blockIdx.y * 64;
  int tid = threadIdx.x;
  if (tid < 64) {
    int o = o0 + tid;
    double cnt = (double)(BB * NN);
    double mean = stats[o] / cnt;
    double var = stats[512 + o] / cnt - mean * mean;
    if (var < 0.0) var = 0.0;
    double rstd = 1.0 / sqrt(var + 1e-5);
    double s = (double)g5[o] * rstd;
    scs[tid] = s;
    scc[tid] = (double)b5[o] - mean * s;
  }
  __syncthreads();
  for (int r = 0; r < 16; ++r) {
    int li = tid + r * 256;
    int nl = li >> 6, ol = li & 63;
    float v = y5[((size_t)b * NN + n0 + nl) * 512 + o0 + ol];
    float a = (float)(scs[ol] * (double)v + scc[ol]);
    a = (a >= 0.f) ? a : NEG_SLOPE * a;
    tile[nl][ol] = a;
  }
  __syncthreads();
  for (int r = 0; r < 16; ++r) {
    int li = tid + r * 256;
    int ol = li >> 6, nl = li & 63;
    out[((size_t)b * 512 + o0 + ol) * NN + n0 + nl] = tile[nl][ol];
  }
}

// =====================================================================================
// r30 (on 631us best; gram frozen after r23/r28/r29 null results): harvest safe
// launch/traffic fusions. (1) BN stats fused into gemm5's epilogue (quad shfl-reduce
// + atomicAdd) -- k_stats512 deleted (16MB y5 re-read + launch). (2) next-layer
// norms fused into bnapply (wave butterfly over channel lanes): L1/L2 write sq,
// L3 writes rnx with rsqrt -- 3 k_rowsq launches + 3 catd re-reads deleted.
// Everything else byte-identical to r29.
extern "C" void kernel_launch(void* const* d_in, const int* in_sizes, int n_in,
                              void* d_out, int out_size, void* d_ws, size_t ws_size,
                              hipStream_t stream) {
  const float* x = (const float*)d_in[0];
  const float* y = (const float*)d_in[1];
  const float* w1 = (const float*)d_in[2];
  const float* w2 = (const float*)d_in[3];
  const float* w3 = (const float*)d_in[4];
  const float* w4 = (const float*)d_in[5];
  const float* w5 = (const float*)d_in[6];
  const float* g1 = (const float*)d_in[7];
  const float* b1 = (const float*)d_in[8];
  const float* g2 = (const float*)d_in[9];
  const float* b2 = (const float*)d_in[10];
  const float* g3 = (const float*)d_in[11];
  const float* b3 = (const float*)d_in[12];
  const float* g4 = (const float*)d_in[13];
  const float* b4 = (const float*)d_in[14];
  const float* g5 = (const float*)d_in[15];
  const float* b5 = (const float*)d_in[16];

  char* base = (char*)d_ws;
  size_t off = 0;
  auto alloc = [&](size_t bytes) -> char* {
    char* p = base + off;
    off += (bytes + 255) & ~(size_t)255;
    return p;
  };
  double* stAll = (double*)alloc(5 * 1024 * 8);  // 5 disjoint per-layer stat slots
  double* sq = (double*)alloc((size_t)BB * NN * 8);
  double* rnx = (double*)alloc((size_t)BB * NN * 8);
  double* rny = (double*)alloc((size_t)BB * MM * 8);
  int* idxb = (int*)alloc((size_t)BB * NN * KNN * 4);
  int* rowt = (int*)alloc(256 * 4);
  int* colt = (int*)alloc(256 * 4);
  int* pflag = (int*)alloc(256);
  double* xs3d = (double*)alloc((size_t)BB * NN * 3 * 8);
  double* ysd = (double*)alloc((size_t)BB * MM * 128 * 8);
  double* catd = (double*)alloc((size_t)BB * NN * 256 * 8);  // knn channels 0..255
  __hip_bfloat16* cath = (__hip_bfloat16*)alloc((size_t)BB * NN * 512 * 2);
  __hip_bfloat16* w5h = (__hip_bfloat16*)alloc((size_t)512 * 512 * 2);
  double* uu = (double*)alloc((size_t)BB * MM * 256 * 8);  // src term (max O=256)
  double* tt = (double*)alloc((size_t)BB * NN * 256 * 8);  // center term
  size_t kkBatchBytes = (size_t)NN * MM * 8;  // 8 MB per batch (u64 keys)
  size_t avail = (ws_size > off) ? (ws_size - off) : 0;
  int CB = (int)(avail / kkBatchBytes);
  if (CB < 1) CB = 1;
  if (CB > BB) CB = BB;
  u64* KK = (u64*)alloc((size_t)CB * kkBatchBytes);
  float* y5 = (float*)uu;             // layer-5 pre-BN (16MB), uu dead by then
  double* mx = (double*)d_out;        // max_k y (f64, <=16MB == out_size)
  float* outp = (float*)d_out;

  const double cntE = (double)BB * NN * KNN;

  // sym=1: triangular symmetric euclid gram (A==B); else general MODE-2 gram (L4)
  auto knn = [&](const double* A, int lda, const double* Bm, int ldb,
                 const double* sa, const double* sb, int C, int sym) {
    for (int b0 = 0; b0 < BB; b0 += CB) {
      int cb = (BB - b0 < CB) ? (BB - b0) : CB;
      if (sym) {
        k_gram_sym<<<dim3(136, cb), 64, 0, stream>>>(A, lda, sa, KK, C, b0, rowt, colt,
                                                     pflag);
      } else {
        dim3 g(MM / 64, NN / 64, cb);
        k_gram_u<2><<<g, 64, 0, stream>>>(A, lda, Bm, ldb, sa, sb, KK, C, b0, rowt,
                                          colt, pflag);
      }
      k_topk<<<dim3(cb, 256), 256, 0, stream>>>(KK, idxb, b0);
    }
  };

  // nrmmode: 0 none; 1 -> sq (O=64); 2 -> rnx rsqrt (O=128)
  auto edge_layer = [&](const double* ctr, int ldc, const double* src, int ldsrc,
                        int srcNp, const float* w, int CW, const float* g,
                        const float* bb, int C, int O, int coff, double* st,
                        double* nrmout, int nrmmode) {
    k_featmm2<<<dim3(8, 2 * (O / 64), 16), 256, 0, stream>>>(
        src, ldsrc, srcNp, ctr, ldc, w, CW, uu, tt, C, O, rowt, colt, pflag);
    k_gather<<<dim3(O / 64, NN / 16, BB), 256, 0, stream>>>(uu, tt, idxb, st, mx, O,
                                                            srcNp);
    int gsz = (BB * NN * O + 255) / 256;
    if (nrmmode == 1)
      k_bnapply<1><<<gsz, 256, 0, stream>>>(mx, uu, tt, idxb, st, g, bb, cntE, catd,
                                            cath, coff, O, srcNp, nrmout);
    else if (nrmmode == 2)
      k_bnapply<2><<<gsz, 256, 0, stream>>>(mx, uu, tt, idxb, st, g, bb, cntE, catd,
                                            cath, coff, O, srcNp, nrmout);
    else
      k_bnapply<0><<<gsz, 256, 0, stream>>>(mx, uu, tt, idxb, st, g, bb, cntE, catd,
                                            cath, coff, O, srcNp, nrmout);
  };

  // ---- one upfront memset for ALL stat slots + probe + transposes + w5 bf16 ----
  hipMemsetAsync(stAll, 0, 5 * 1024 * 8, stream);
  k_probe_mfma<<<1, 64, 0, stream>>>(rowt, colt, pflag);
  k_transpose_d<<<96, 256, 0, stream>>>(x, xs3d, 3, NN);
  k_transpose_d<<<2048, 256, 0, stream>>>(y, ysd, 128, MM);
  k_cvt_bf16<<<1024, 256, 0, stream>>>(w5, w5h, 512 * 512);

  // ---- layer 1: C=3, O=64 (fused knn, no gram); bnapply emits sq for L2 ----
  k_rowsq<0><<<32, 256, 0, stream>>>(xs3d, 3, 3, sq);
  k_knn3<<<dim3(BB, 256), 256, 0, stream>>>(xs3d, sq, idxb);
  edge_layer(xs3d, 3, xs3d, 3, NN, w1, 6, g1, b1, 3, 64, 0, stAll, sq, 1);

  // ---- layer 2: x1 = catd[:,0:64], C=64, O=64; bnapply emits sq for L3 ----
  knn(catd, 256, catd, 256, sq, sq, 64, 1);
  edge_layer(catd, 256, catd, 256, NN, w2, 128, g2, b2, 64, 64, 64, stAll + 1024, sq,
             1);

  // ---- layer 3: x2 = catd[:,64:128], C=64, O=128; bnapply emits rnx for L4 ----
  knn(catd + 64, 256, catd + 64, 256, sq, sq, 64, 1);
  edge_layer(catd + 64, 256, catd + 64, 256, NN, w3, 128, g3, b3, 64, 128, 128,
             stAll + 2048, rnx, 2);

  // ---- layer 4 (IA): x3 = catd[:,128:256], src = y (cosine knn), C=128, O=256 ----
  k_rowsq<1><<<32, 256, 0, stream>>>(ysd, 128, 128, rny);
  knn(catd + 128, 256, ysd, 128, rnx, rny, 128, 0);
  edge_layer(catd + 128, 256, ysd, 128, MM, w4, 256, g4, b4, 128, 256, 256,
             stAll + 3072, nullptr, 0);

  // ---- layer 5: bf16-MFMA GEMM (stats fused) -> y5, BN, lrelu, transpose ----
  double* st5 = stAll + 4096;
  k_gemm5_mfma<<<dim3(8, 16, 8), 64, 0, stream>>>(cath, w5h, y5, st5);
  k_final5b<<<dim3(16, 8, 8), 256, 0, stream>>>(y5, st5, g5, b5, outp);
}

// Round 18
// 581.336 us; speedup vs baseline: 1.2511x; 1.0079x over previous
//
#include <hip/hip_runtime.h>
#include <hip/hip_bf16.h>

#define KNN 20
#define NEG_SLOPE 0.2f

constexpr int BB = 8;
constexpr int NN = 1024;
constexpr int MM = 1024;

typedef short bf16x8 __attribute__((ext_vector_type(8)));
typedef float f32x4 __attribute__((ext_vector_type(4)));
typedef double f64x4 __attribute__((ext_vector_type(4)));
typedef unsigned long long u64;

// ================= top-20 selection via exact u64 keys =================
// Monotone f64->u64 map, low 10 bits replaced by inverted column index.
// Key order == f64 descending order with tie -> lower idx (jax top_k semantics).
__device__ __forceinline__ u64 pack_key64(double d, int j) {
  u64 u = (u64)__double_as_longlong(d);
  u = (u & 0x8000000000000000ULL) ? ~u : (u | 0x8000000000000000ULL);
  return (u & ~(u64)1023) | (u64)(1023 - j);
}

// Per-wave top-20: each lane holds 16 keys; Batcher odd-even mergesort (desc),
// then 20 extraction rounds (wave-max + winner-lane shift). Exact, no fallback.
__device__ __forceinline__ void topk20_u64(u64 (&s)[16], int lane, int* op) {
#pragma unroll
  for (int p = 1; p < 16; p <<= 1) {
#pragma unroll
    for (int k = p; k >= 1; k >>= 1) {
#pragma unroll
      for (int j = k % p; j + k < 16; j += 2 * k) {
#pragma unroll
        for (int i = 0; i < k; ++i) {
          int a = j + i, b = j + i + k;
          if (b < 16 && (a / (2 * p)) == (b / (2 * p))) {
            u64 hi = s[a] > s[b] ? s[a] : s[b];
            u64 lo = s[a] > s[b] ? s[b] : s[a];
            s[a] = hi;
            s[b] = lo;
          }
        }
      }
    }
  }
#pragma unroll
  for (int r = 0; r < KNN; ++r) {
    u64 win = s[0];
#pragma unroll
    for (int off = 32; off > 0; off >>= 1) {
      u64 o = __shfl_xor(win, off, 64);
      win = o > win ? o : win;
    }
    if (lane == 0) op[r] = 1023 - (int)(win & (u64)1023);
    if (s[0] == win) {
#pragma unroll
      for (int i = 0; i < 15; ++i) s[i] = s[i + 1];
      s[15] = 0ULL;
    }
  }
}

// ======== f64 MFMA layout self-probe + decode, fused (one wave, ~3us) ========
__global__ void k_probe_mfma(int* __restrict__ rowt, int* __restrict__ colt,
                             int* __restrict__ flag) {
  __shared__ int cnt[256];
  __shared__ int oksh;
  int tid = threadIdx.x;  // 64 threads
  if (tid == 0) oksh = 1;
  for (int e = tid; e < 256; e += 64) cnt[e] = 0;
  __syncthreads();
  int lane = tid & 63;
  f64x4 z = {0.0, 0.0, 0.0, 0.0};
  double ai = (double)(lane & 15);
  double p3 = 1.0, p5 = 1.0;
  int kq = lane >> 4;
  for (int t = 0; t < kq; ++t) { p3 *= 3.0; p5 *= 5.0; }
  f64x4 d1 = __builtin_amdgcn_mfma_f64_16x16x4f64(ai, 1.0, z, 0, 0, 0);
  f64x4 d2 = __builtin_amdgcn_mfma_f64_16x16x4f64(1.0, ai, z, 0, 0, 0);
  f64x4 d3 = __builtin_amdgcn_mfma_f64_16x16x4f64(p3, p5, z, 0, 0, 0);
  bool ok = true;
  int ri[4], ci[4];
#pragma unroll
  for (int r = 0; r < 4; ++r) {
    double va = d1[r], vb = d2[r], vp = d3[r];
    int i = (int)(va * 0.25);
    int j = (int)(vb * 0.25);
    bool e_ok = (i >= 0) && (i < 16) && (j >= 0) && (j < 16) &&
                (va == 4.0 * (double)i) && (vb == 4.0 * (double)j) && (vp == 3616.0);
    if (e_ok) {
      atomicAdd(&cnt[i * 16 + j], 1);
    } else {
      ok = false;
      i = 0;
      j = 0;
    }
    ri[r] = i;
    ci[r] = j;
  }
  if (!ok) atomicExch(&oksh, 0);
  __syncthreads();
  bool bij = true;
  for (int e = tid; e < 256; e += 64)
    if (cnt[e] != 1) bij = false;
  if (!bij) atomicExch(&oksh, 0);
  __syncthreads();
#pragma unroll
  for (int r = 0; r < 4; ++r) {
    rowt[lane * 4 + r] = ri[r];
    colt[lane * 4 + r] = ci[r];
  }
  if (tid == 0) *flag = oksh;
}

// ---------------- transpose f32 -> f64: (B,C,Np) -> (B,Np,C) ----------------
__global__ __launch_bounds__(256) void k_transpose_d(
    const float* __restrict__ in, double* __restrict__ out, int C, int Np) {
  int total = BB * C * Np;
  for (int t = blockIdx.x * 256 + threadIdx.x; t < total; t += gridDim.x * 256) {
    int c = t % C;
    int n = (t / C) % Np;
    int b = t / (C * Np);
    out[t] = (double)in[((size_t)b * C + c) * Np + n];
  }
}

// ---------------- f32 -> bf16 convert ----------------
__global__ __launch_bounds__(256) void k_cvt_bf16(
    const float* __restrict__ in, __hip_bfloat16* __restrict__ out, int n) {
  int i = blockIdx.x * 256 + threadIdx.x;
  if (i < n) out[i] = __float2bfloat16(in[i]);
}

// ------- per-point squared norm (RECIP=0) or reciprocal norm (RECIP=1), f64 -------
template <int RECIP>
__global__ __launch_bounds__(256) void k_rowsq(
    const double* __restrict__ A, int ld, int C, double* __restrict__ sq) {
  int p = blockIdx.x * 256 + threadIdx.x;
  if (p >= BB * NN) return;
  const double* row = A + (size_t)p * ld;
  double s = 0.0;
  for (int c = 0; c < C; ++c) { double v = row[c]; s += v * v; }
  if (RECIP) {
    sq[p] = 1.0 / fmax(sqrt(s), 1e-12);
  } else {
    sq[p] = s;
  }
}

// ---- fused L1 knn (C=3): all points in LDS (f64), u64-key topk (exact) ----
__global__ __launch_bounds__(256) void k_knn3(
    const double* __restrict__ xs3, const double* __restrict__ sq, int* __restrict__ idx) {
  __shared__ double P[NN * 3];
  int b = blockIdx.x;
  const double* Xb = xs3 + (size_t)b * NN * 3;
  int tid = threadIdx.x;
  for (int t = tid; t < NN * 3; t += 256) P[t] = Xb[t];
  __syncthreads();
  int wave = tid >> 6, lane = tid & 63;
  int i = blockIdx.y * 4 + wave;
  double xi = P[i * 3], yi = P[i * 3 + 1], zi = P[i * 3 + 2];
  double sqi = sq[b * NN + i];
  u64 s[16];
#pragma unroll
  for (int m = 0; m < 16; ++m) {
    int j = m * 64 + lane;
    double d = fma(xi, P[j * 3], 0.0);
    d = fma(yi, P[j * 3 + 1], d);
    d = fma(zi, P[j * 3 + 2], d);
    s[m] = pack_key64(2.0 * d - sqi - sq[b * NN + j], j);
  }
  int* op = idx + ((size_t)b * NN + i) * KNN;
  topk20_u64(s, lane, op);
}

// ---- gram (r22-verified body, r27-verified grid: batch in blockIdx.x gives
// near-perfect batch<->XCD affinity with 8 batches -- r29's batch-slowest
// reorder measured WORSE: 56.4->58.5us, FETCH 8.3->37MB; reverted).
// ONE WAVE per WG, 64x64 tile, K-block 8, barrier-free in-wave DOUBLE buffer.
// Probe-decoded D tables; VALU fallback. MODE 1: 2*dot-sq-sq; MODE 2: dot*rn*rn
template <int MODE>
__global__ __launch_bounds__(64, 2) void k_gram_u(
    const double* __restrict__ A, int lda, const double* __restrict__ Bm, int ldb,
    const double* __restrict__ sqA, const double* __restrict__ sqB,
    u64* __restrict__ kk, int C, int b0, const int* __restrict__ rowt,
    const int* __restrict__ colt, const int* __restrict__ flag) {
  __shared__ double As[2][8][69];
  __shared__ double Bs[2][8][69];
  int bl = blockIdx.x;
  int bg = b0 + bl;
  int j0 = blockIdx.y * 64;
  int i0 = blockIdx.z * 64;
  const double* Ab = A + (size_t)bg * NN * lda;
  const double* Bb = Bm + (size_t)bg * MM * ldb;
  int lane = threadIdx.x;
  if (*flag) {
    int lm = lane & 15, lq = lane >> 4;
    int k8 = lane & 7, r8 = lane >> 3;  // staging coords: k fixed, rows r8+8r
    const double* pa = Ab + (size_t)(i0 + r8) * lda + k8;
    const double* pb = Bb + (size_t)(j0 + r8) * ldb + k8;
    f64x4 acc[4][4] = {};
    double ra[8], rb[8];
    // prologue: stage K-block 0 into buffer 0
#pragma unroll
    for (int r = 0; r < 8; ++r) {
      ra[r] = pa[(size_t)(8 * r) * lda];
      rb[r] = pb[(size_t)(8 * r) * ldb];
    }
#pragma unroll
    for (int r = 0; r < 8; ++r) {
      As[0][k8][r8 + 8 * r] = ra[r];
      Bs[0][k8][r8 + 8 * r] = rb[r];
    }
    int nblk = C >> 3;
    for (int cb = 0; cb < nblk; ++cb) {
      int buf = cb & 1;
      bool pf = (cb + 1 < nblk);
      if (pf) {  // issue next block's loads; vmcnt wait lands after the MFMAs
        int c0 = (cb + 1) << 3;
#pragma unroll
        for (int r = 0; r < 8; ++r) {
          ra[r] = pa[(size_t)(8 * r) * lda + c0];
          rb[r] = pb[(size_t)(8 * r) * ldb + c0];
        }
      }
#pragma unroll
      for (int kc = 0; kc < 2; ++kc) {
        double a_[4], b_[4];
#pragma unroll
        for (int s = 0; s < 4; ++s) {
          a_[s] = As[buf][kc * 4 + lq][s * 16 + lm];
          b_[s] = Bs[buf][kc * 4 + lq][s * 16 + lm];
        }
#pragma unroll
        for (int si = 0; si < 4; ++si)
#pragma unroll
          for (int sj = 0; sj < 4; ++sj)
            acc[si][sj] = __builtin_amdgcn_mfma_f64_16x16x4f64(a_[si], b_[sj],
                                                               acc[si][sj], 0, 0, 0);
      }
      if (pf) {  // fill the other buffer (per-wave DS in-order: no barrier)
        int nb = buf ^ 1;
#pragma unroll
        for (int r = 0; r < 8; ++r) {
          As[nb][k8][r8 + 8 * r] = ra[r];
          Bs[nb][k8][r8 + 8 * r] = rb[r];
        }
      }
    }
    int rta[4], cta[4];
#pragma unroll
    for (int r = 0; r < 4; ++r) {
      rta[r] = rowt[lane * 4 + r];
      cta[r] = colt[lane * 4 + r];
    }
#pragma unroll
    for (int si = 0; si < 4; ++si) {
#pragma unroll
      for (int sj = 0; sj < 4; ++sj) {
#pragma unroll
        for (int r = 0; r < 4; ++r) {
          int i = i0 + si * 16 + rta[r];
          int j = j0 + sj * 16 + cta[r];
          double v = acc[si][sj][r];
          if (MODE == 1)
            v = 2.0 * v - sqA[(size_t)bg * NN + i] - sqB[(size_t)bg * MM + j];
          if (MODE == 2) v = v * sqA[(size_t)bg * NN + i] * sqB[(size_t)bg * MM + j];
          kk[((size_t)bl * NN + i) * MM + j] = pack_key64(v, j);
        }
      }
    }
  } else {
    int lr = lane >> 3, lc = lane & 7;  // 8x8 lane grid, 8x8 outputs each
    double acc2[8][8] = {};
    for (int c0 = 0; c0 < C; c0 += 8) {
      if (c0) __syncthreads();
      for (int r = 0; r < 8; ++r) {
        int li = lane + r * 64;
        int row = li >> 3, k = li & 7;
        As[0][k][row] = Ab[(size_t)(i0 + row) * lda + c0 + k];
        Bs[0][k][row] = Bb[(size_t)(j0 + row) * ldb + c0 + k];
      }
      __syncthreads();
#pragma unroll
      for (int k = 0; k < 8; ++k) {
        double a_[8], b_[8];
#pragma unroll
        for (int t = 0; t < 8; ++t) {
          a_[t] = As[0][k][lr * 8 + t];
          b_[t] = Bs[0][k][lc * 8 + t];
        }
#pragma unroll
        for (int ii = 0; ii < 8; ++ii)
#pragma unroll
          for (int jj = 0; jj < 8; ++jj)
            acc2[ii][jj] = fma(a_[ii], b_[jj], acc2[ii][jj]);
      }
    }
    for (int ii = 0; ii < 8; ++ii) {
      int i = i0 + lr * 8 + ii;
      double qa = sqA[(size_t)bg * NN + i];
      for (int jj = 0; jj < 8; ++jj) {
        int j = j0 + lc * 8 + jj;
        double v = acc2[ii][jj];
        if (MODE == 1) v = 2.0 * v - qa - sqB[(size_t)bg * MM + j];
        if (MODE == 2) v = v * qa * sqB[(size_t)bg * MM + j];
        kk[((size_t)bl * NN + i) * MM + j] = pack_key64(v, j);
      }
    }
  }
}

// ---- symmetric euclid gram (A==B, layers 2/3): triangular 136-block grid,
// r22-verified inner loop, r27-verified grid (batch in blockIdx.x).
// Off-diagonal tiles also write mirrored key kk[j][i]=pack(v,i).
__global__ __launch_bounds__(64, 2) void k_gram_sym(
    const double* __restrict__ A, int lda, const double* __restrict__ sqA,
    u64* __restrict__ kk, int C, int b0, const int* __restrict__ rowt,
    const int* __restrict__ colt, const int* __restrict__ flag) {
  __shared__ double As[2][8][69];
  __shared__ double Bs[2][8][69];
  int p = blockIdx.y;  // 0..135 triangular pair index
  int bl = blockIdx.x;
  int bg = b0 + bl;
  int r = (int)((sqrtf(8.f * p + 1.f) - 1.f) * 0.5f);
  while ((r + 1) * (r + 2) / 2 <= p) ++r;
  while (r * (r + 1) / 2 > p) --r;
  int cc = p - r * (r + 1) / 2;
  int i0 = r * 64, j0 = cc * 64;
  const double* Ab = A + (size_t)bg * NN * lda;
  int lane = threadIdx.x;
  if (*flag) {
    int lm = lane & 15, lq = lane >> 4;
    int k8 = lane & 7, r8 = lane >> 3;
    const double* pa = Ab + (size_t)(i0 + r8) * lda + k8;
    const double* pb = Ab + (size_t)(j0 + r8) * lda + k8;
    f64x4 acc[4][4] = {};
    double ra[8], rb[8];
#pragma unroll
    for (int r_ = 0; r_ < 8; ++r_) {
      ra[r_] = pa[(size_t)(8 * r_) * lda];
      rb[r_] = pb[(size_t)(8 * r_) * lda];
    }
#pragma unroll
    for (int r_ = 0; r_ < 8; ++r_) {
      As[0][k8][r8 + 8 * r_] = ra[r_];
      Bs[0][k8][r8 + 8 * r_] = rb[r_];
    }
    int nblk = C >> 3;
    for (int cb = 0; cb < nblk; ++cb) {
      int buf = cb & 1;
      bool pf = (cb + 1 < nblk);
      if (pf) {
        int c0 = (cb + 1) << 3;
#pragma unroll
        for (int r_ = 0; r_ < 8; ++r_) {
          ra[r_] = pa[(size_t)(8 * r_) * lda + c0];
          rb[r_] = pb[(size_t)(8 * r_) * lda + c0];
        }
      }
#pragma unroll
      for (int kc = 0; kc < 2; ++kc) {
        double a_[4], b_[4];
#pragma unroll
        for (int s = 0; s < 4; ++s) {
          a_[s] = As[buf][kc * 4 + lq][s * 16 + lm];
          b_[s] = Bs[buf][kc * 4 + lq][s * 16 + lm];
        }
#pragma unroll
        for (int si = 0; si < 4; ++si)
#pragma unroll
          for (int sj = 0; sj < 4; ++sj)
            acc[si][sj] = __builtin_amdgcn_mfma_f64_16x16x4f64(a_[si], b_[sj],
                                                               acc[si][sj], 0, 0, 0);
      }
      if (pf) {
        int nb = buf ^ 1;
#pragma unroll
        for (int r_ = 0; r_ < 8; ++r_) {
          As[nb][k8][r8 + 8 * r_] = ra[r_];
          Bs[nb][k8][r8 + 8 * r_] = rb[r_];
        }
      }
    }
    int rta[4], cta[4];
#pragma unroll
    for (int r_ = 0; r_ < 4; ++r_) {
      rta[r_] = rowt[lane * 4 + r_];
      cta[r_] = colt[lane * 4 + r_];
    }
    bool mir = (i0 != j0);
#pragma unroll
    for (int si = 0; si < 4; ++si) {
#pragma unroll
      for (int sj = 0; sj < 4; ++sj) {
#pragma unroll
        for (int r_ = 0; r_ < 4; ++r_) {
          int i = i0 + si * 16 + rta[r_];
          int j = j0 + sj * 16 + cta[r_];
          double v = 2.0 * acc[si][sj][r_] - sqA[(size_t)bg * NN + i] -
                     sqA[(size_t)bg * NN + j];
          kk[((size_t)bl * NN + i) * MM + j] = pack_key64(v, j);
          if (mir) kk[((size_t)bl * NN + j) * MM + i] = pack_key64(v, i);
        }
      }
    }
  } else {
    int lr = lane >> 3, lc = lane & 7;
    double acc2[8][8] = {};
    for (int c0 = 0; c0 < C; c0 += 8) {
      if (c0) __syncthreads();
      for (int r_ = 0; r_ < 8; ++r_) {
        int li = lane + r_ * 64;
        int row = li >> 3, k = li & 7;
        As[0][k][row] = Ab[(size_t)(i0 + row) * lda + c0 + k];
        Bs[0][k][row] = Ab[(size_t)(j0 + row) * lda + c0 + k];
      }
      __syncthreads();
#pragma unroll
      for (int k = 0; k < 8; ++k) {
        double a_[8], b_[8];
#pragma unroll
        for (int t = 0; t < 8; ++t) {
          a_[t] = As[0][k][lr * 8 + t];
          b_[t] = Bs[0][k][lc * 8 + t];
        }
#pragma unroll
        for (int ii = 0; ii < 8; ++ii)
#pragma unroll
          for (int jj = 0; jj < 8; ++jj)
            acc2[ii][jj] = fma(a_[ii], b_[jj], acc2[ii][jj]);
      }
    }
    bool mir = (i0 != j0);
    for (int ii = 0; ii < 8; ++ii) {
      int i = i0 + lr * 8 + ii;
      double qa = sqA[(size_t)bg * NN + i];
      for (int jj = 0; jj < 8; ++jj) {
        int j = j0 + lc * 8 + jj;
        double v = 2.0 * acc2[ii][jj] - qa - sqA[(size_t)bg * NN + j];
        kk[((size_t)bl * NN + i) * MM + j] = pack_key64(v, j);
        if (mir) kk[((size_t)bl * NN + j) * MM + i] = pack_key64(v, i);
      }
    }
  }
}

// ------- top-20 per row from exact u64 keys; no fallback -------
__global__ __launch_bounds__(256) void k_topk(const u64* __restrict__ kk,
                                              int* __restrict__ idx, int b0) {
  int wave = threadIdx.x >> 6;
  int lane = threadIdx.x & 63;
  int bl = blockIdx.x;
  int row = blockIdx.y * 4 + wave;
  const u64* rp = kk + ((size_t)bl * NN + row) * MM;
  u64 s[16];
#pragma unroll
  for (int m = 0; m < 16; ++m) s[m] = rp[m * 64 + lane];
  int* op = idx + ((size_t)(b0 + bl) * NN + row) * KNN;
  topk20_u64(s, lane, op);
}

// --- fused per-point feature matmul (f64), both modes in one launch (4-wave,
// 1-D 256-thread block) ---
__global__ __launch_bounds__(256) void k_featmm2(
    const double* __restrict__ src0, int ld0, int Np0,
    const double* __restrict__ src1, int ld1,
    const float* __restrict__ w, int CW,
    double* __restrict__ out0, double* __restrict__ out1, int C, int O,
    const int* __restrict__ rowt, const int* __restrict__ colt,
    const int* __restrict__ flag) {
  __shared__ double As[16][68];
  __shared__ double Ws[16][68];
  int nbo = O >> 6;
  int b = blockIdx.x;
  int mode = blockIdx.y >= nbo;
  int o0 = (blockIdx.y - (mode ? nbo : 0)) * 64;
  int j0 = blockIdx.z * 64;
  const double* src = mode ? src1 : src0;
  int lds_ = mode ? ld1 : ld0;
  int Np = mode ? NN : Np0;
  double* out = mode ? out1 : out0;
  int tid = threadIdx.x;
  const double* Sb = src + (size_t)b * Np * lds_;
  if (*flag) {
    int lane = tid & 63, wv = tid >> 6;
    int lm = lane & 15, lq = lane >> 4;
    f64x4 acc[4] = {};
    for (int c0 = 0; c0 < C; c0 += 16) {
      if (c0) __syncthreads();
      for (int r = 0; r < 4; ++r) {
        int li = tid + r * 256;
        int row = li >> 4, k = li & 15;
        int c = c0 + k;
        As[k][row] = (c < C) ? Sb[(size_t)(j0 + row) * lds_ + c] : 0.0;
        double wvv = 0.0;
        if (c < C) {
          const float* wr = w + (size_t)(o0 + row) * CW;
          wvv = (mode == 0) ? (double)wr[c] : ((double)wr[C + c] - (double)wr[c]);
        }
        Ws[k][row] = wvv;
      }
      __syncthreads();
#pragma unroll
      for (int kc = 0; kc < 4; ++kc) {
        double a = As[kc * 4 + lq][wv * 16 + lm];
#pragma unroll
        for (int t = 0; t < 4; ++t) {
          double bb = Ws[kc * 4 + lq][t * 16 + lm];
          acc[t] = __builtin_amdgcn_mfma_f64_16x16x4f64(a, bb, acc[t], 0, 0, 0);
        }
      }
    }
    int rta[4], cta[4];
#pragma unroll
    for (int r = 0; r < 4; ++r) {
      rta[r] = rowt[lane * 4 + r];
      cta[r] = colt[lane * 4 + r];
    }
#pragma unroll
    for (int t = 0; t < 4; ++t) {
#pragma unroll
      for (int r = 0; r < 4; ++r) {
        int j = j0 + wv * 16 + rta[r];
        int o = o0 + t * 16 + cta[r];
        out[((size_t)b * Np + j) * O + o] = acc[t][r];
      }
    }
  } else {
    int tx = tid & 15, ty = tid >> 4;
    double acc[4][4] = {};
    for (int c0 = 0; c0 < C; c0 += 16) {
      if (c0) __syncthreads();
      for (int r = 0; r < 4; ++r) {
        int li = tid + r * 256;
        int row = li >> 4, k = li & 15;
        int c = c0 + k;
        As[k][row] = (c < C) ? Sb[(size_t)(j0 + row) * lds_ + c] : 0.0;
        double wvv = 0.0;
        if (c < C) {
          const float* wr = w + (size_t)(o0 + row) * CW;
          wvv = (mode == 0) ? (double)wr[c] : ((double)wr[C + c] - (double)wr[c]);
        }
        Ws[k][row] = wvv;
      }
      __syncthreads();
#pragma unroll
      for (int k = 0; k < 16; ++k) {
        double a_[4], b_[4];
#pragma unroll
        for (int ii = 0; ii < 4; ++ii) a_[ii] = As[k][ty * 4 + ii];
#pragma unroll
        for (int jj = 0; jj < 4; ++jj) b_[jj] = Ws[k][tx * 4 + jj];
#pragma unroll
        for (int ii = 0; ii < 4; ++ii)
#pragma unroll
          for (int jj = 0; jj < 4; ++jj)
            acc[ii][jj] = fma(a_[ii], b_[jj], acc[ii][jj]);
      }
    }
    for (int ii = 0; ii < 4; ++ii) {
      int j = j0 + ty * 4 + ii;
      double* op = &out[((size_t)b * Np + j) * O + o0 + tx * 4];
      double2 v0, v1;
      v0.x = acc[ii][0];
      v0.y = acc[ii][1];
      v1.x = acc[ii][2];
      v1.y = acc[ii][3];
      *(double2*)op = v0;
      *(double2*)(op + 2) = v1;
    }
  }
}

// ---- layer-5 GEMM via bf16 MFMA: ONE WAVE per WG, 64x64 tile, K=512 unrolled.
// BN stats fused into epilogue (quad shfl-reduce + atomicAdd) -- replaces
// the separate k_stats512 pass (16MB y5 re-read + launch).
__global__ __launch_bounds__(64, 2) void k_gemm5_mfma(
    const __hip_bfloat16* __restrict__ cath, const __hip_bfloat16* __restrict__ w5h,
    float* __restrict__ out, double* __restrict__ stats) {
  int b = blockIdx.x;
  int j0 = blockIdx.y * 64;
  int o0 = blockIdx.z * 64;
  int lane = threadIdx.x;
  int m = lane & 15;
  int quad = lane >> 4;
  const __hip_bfloat16* arow = cath + ((size_t)(b * NN + j0 + m)) * 512 + quad * 8;
  const __hip_bfloat16* brow = w5h + ((size_t)(o0 + m)) * 512 + quad * 8;
  f32x4 acc[4][4] = {};
#pragma unroll
  for (int c0 = 0; c0 < 512; c0 += 32) {
    bf16x8 a[4], bb[4];
#pragma unroll
    for (int s = 0; s < 4; ++s) {
      a[s] = *(const bf16x8*)(arow + (size_t)s * 16 * 512 + c0);
      bb[s] = *(const bf16x8*)(brow + (size_t)s * 16 * 512 + c0);
    }
#pragma unroll
    for (int si = 0; si < 4; ++si)
#pragma unroll
      for (int sj = 0; sj < 4; ++sj)
        acc[si][sj] =
            __builtin_amdgcn_mfma_f32_16x16x32_bf16(a[si], bb[sj], acc[si][sj], 0, 0, 0);
  }
  // D layout (verified): row = quad*4 + r, col = m, per 16x16 subtile
#pragma unroll
  for (int si = 0; si < 4; ++si) {
    float* ob = &out[((size_t)(b * NN + j0 + si * 16 + quad * 4)) * 512 + o0 + m];
#pragma unroll
    for (int sj = 0; sj < 4; ++sj)
#pragma unroll
      for (int r = 0; r < 4; ++r)
        ob[(size_t)r * 512 + sj * 16] = acc[si][sj][r];
  }
  // fused BN stats: per-lane column partials over this wave's 64 j's
#pragma unroll
  for (int sj = 0; sj < 4; ++sj) {
    float s1 = 0.f, s2 = 0.f;
#pragma unroll
    for (int si = 0; si < 4; ++si)
#pragma unroll
      for (int r = 0; r < 4; ++r) {
        float v = acc[si][sj][r];
        s1 += v;
        s2 = fmaf(v, v, s2);
      }
    s1 += __shfl_xor(s1, 16, 64);
    s1 += __shfl_xor(s1, 32, 64);
    s2 += __shfl_xor(s2, 16, 64);
    s2 += __shfl_xor(s2, 32, 64);
    if (quad == 0) {
      int o = o0 + sj * 16 + m;
      atomicAdd(&stats[o], (double)s1);
      atomicAdd(&stats[512 + o], (double)s2);
    }
  }
}

// ------- fused gather (f64): per (n,o) max_k y, accumulate BN stats -------
// Grid (O/64, NN/16, BB): b slowest -> per-XCD L2 residency of batch slices
// (r27-measured win; 256 blocks/batch regime differs from gram's 8-in-x).
__global__ __launch_bounds__(256) void k_gather(
    const double* __restrict__ u, const double* __restrict__ t, const int* __restrict__ idx,
    double* __restrict__ stats, double* __restrict__ mx, int O, int srcNp) {
  __shared__ int lidx[16 * KNN];
  __shared__ double rs[256];
  __shared__ double rq[256];
  int b = blockIdx.z;
  int n0 = blockIdx.y * 16;
  int o0 = blockIdx.x * 64;
  int tid = threadIdx.x;
  int lane = tid & 63, nsl = tid >> 6;
  for (int w = tid; w < 16 * KNN; w += 256)
    lidx[w] = idx[((size_t)b * NN + n0) * KNN + w];
  __syncthreads();
  int oo = o0 + lane;
  double s1 = 0.0, s2 = 0.0;
  for (int ns = nsl; ns < 16; ns += 4) {
    size_t row = (size_t)b * NN + n0 + ns;
    double tv = t[row * O + oo];
    double mxv = -INFINITY;
    double a1 = 0.0, a2 = 0.0;
#pragma unroll
    for (int k = 0; k < KNN; ++k) {
      int j = lidx[ns * KNN + k];
      double yv = u[((size_t)b * srcNp + j) * O + oo] + tv;
      mxv = fmax(mxv, yv);
      a1 += yv;
      a2 = fma(yv, yv, a2);
    }
    mx[row * O + oo] = mxv;
    s1 += a1;
    s2 += a2;
  }
  rs[tid] = s1;
  rq[tid] = s2;
  __syncthreads();
  if (tid < 64) {
    s1 = rs[tid] + rs[tid + 64] + rs[tid + 128] + rs[tid + 192];
    s2 = rq[tid] + rq[tid + 64] + rq[tid + 128] + rq[tid + 192];
    atomicAdd(&stats[o0 + tid], s1);
    atomicAdd(&stats[O + o0 + tid], s2);
  }
}

// --- apply BN+lrelu to stored max (f64); BN fold in LDS. NRM: fused next-layer
// norm -- 0: none; 1: Sum a^2 -> nrm[p] (O==64, one wave = one point);
// 2: 1/sqrt(Sum a^2) -> nrm[p] (O==128, two waves combine via LDS).
template <int NRM>
__global__ __launch_bounds__(256) void k_bnapply(
    const double* __restrict__ mx, const double* __restrict__ u, const double* __restrict__ t,
    const int* __restrict__ idx, const double* __restrict__ stats,
    const float* __restrict__ gamma, const float* __restrict__ beta, double cnt,
    double* __restrict__ catd, __hip_bfloat16* __restrict__ cath, int coff, int O,
    int srcNp, double* __restrict__ nrm) {
  __shared__ double scs[256];
  __shared__ double scc[256];
  __shared__ double part[4];
  int tid = threadIdx.x;
  if (tid < O) {
    double mean = stats[tid] / cnt;
    double var = stats[O + tid] / cnt - mean * mean;
    if (var < 0.0) var = 0.0;
    double rstd = 1.0 / sqrt(var + 1e-5);
    double s = (double)gamma[tid] * rstd;
    scs[tid] = s;
    scc[tid] = (double)beta[tid] - mean * s;
  }
  __syncthreads();
  int i = blockIdx.x * 256 + tid;
  int oo = i % O;
  int n = (i / O) % NN;
  int b = i / (O * NN);
  double s = scs[oo], c = scc[oo];
  double v;
  if (s >= 0.0) {
    v = mx[i];
  } else {  // monotone-decreasing transform needs min_k y (never hit with gamma=1)
    double tv = t[i];
    double mn = INFINITY;
    for (int k = 0; k < KNN; ++k) {
      int j = idx[((size_t)b * NN + n) * KNN + k];
      mn = fmin(mn, u[((size_t)b * srcNp + j) * O + oo] + tv);
    }
    v = mn;
  }
  double a = s * v + c;
  a = (a >= 0.0) ? a : 0.2 * a;
  size_t ci = ((size_t)b * NN + n) * 512 + coff + oo;
  cath[ci] = __float2bfloat16((float)a);
  if (coff < 256) catd[((size_t)b * NN + n) * 256 + coff + oo] = a;
  if (NRM > 0) {
    double q = a * a;
#pragma unroll
    for (int off = 32; off > 0; off >>= 1) q += __shfl_xor(q, off, 64);
    if (NRM == 1) {  // O==64: one wave == one point
      if ((tid & 63) == 0) nrm[i >> 6] = q;
    } else {  // NRM==2, O==128: two waves per point
      int wv = tid >> 6;
      if ((tid & 63) == 0) part[wv] = q;
      __syncthreads();
      if ((tid & 127) == 0) {
        double tot = part[wv] + part[wv + 1];
        nrm[i >> 7] = 1.0 / fmax(sqrt(tot), 1e-12);
      }
    }
  }
}

// --- layer 5 finalize: BN fold in LDS, BN+lrelu on stored y5, transpose, store ---
__global__ __launch_bounds__(256) void k_final5b(
    const float* __restrict__ y5, const double* __restrict__ stats,
    const float* __restrict__ g5, const float* __restrict__ b5,
    float* __restrict__ out) {
  __shared__ float tile[64][65];
  __shared__ double scs[64];
  __shared__ double scc[64];
  int b = blockIdx.z;
  int n0 = blockIdx.x * 64;
  int o0 = blockIdx.y * 64;
  int tid = threadIdx.x;
  if (tid < 64) {
    int o = o0 + tid;
    double cnt = (double)(BB * NN);
    double mean = stats[o] / cnt;
    double var = stats[512 + o] / cnt - mean * mean;
    if (var < 0.0) var = 0.0;
    double rstd = 1.0 / sqrt(var + 1e-5);
    double s = (double)g5[o] * rstd;
    scs[tid] = s;
    scc[tid] = (double)b5[o] - mean * s;
  }
  __syncthreads();
  for (int r = 0; r < 16; ++r) {
    int li = tid + r * 256;
    int nl = li >> 6, ol = li & 63;
    float v = y5[((size_t)b * NN + n0 + nl) * 512 + o0 + ol];
    float a = (float)(scs[ol] * (double)v + scc[ol]);
    a = (a >= 0.f) ? a : NEG_SLOPE * a;
    tile[nl][ol] = a;
  }
  __syncthreads();
  for (int r = 0; r < 16; ++r) {
    int li = tid + r * 256;
    int ol = li >> 6, nl = li & 63;
    out[((size_t)b * 512 + o0 + ol) * NN + n0 + nl] = tile[nl][ol];
  }
}

// =====================================================================================
// r31 (on r30 best, 585.9us): single delta -- revert gram/sym grids to r27's
// batch-FASTEST form. r29's batch-slowest reorder measurably hurt the gram itself
// (56.4->58.5us, FETCH 8.3->37MB): with exactly 8 batches in blockIdx.x the RR
// dispatch already gave near-perfect batch<->XCD affinity (each XCD's L2 holds ~2
// batch panels); reordering broke it. Gather keeps b-slowest (256 blocks/batch
// regime, r27-measured -14us). Everything else byte-identical to r30.
extern "C" void kernel_launch(void* const* d_in, const int* in_sizes, int n_in,
                              void* d_out, int out_size, void* d_ws, size_t ws_size,
                              hipStream_t stream) {
  const float* x = (const float*)d_in[0];
  const float* y = (const float*)d_in[1];
  const float* w1 = (const float*)d_in[2];
  const float* w2 = (const float*)d_in[3];
  const float* w3 = (const float*)d_in[4];
  const float* w4 = (const float*)d_in[5];
  const float* w5 = (const float*)d_in[6];
  const float* g1 = (const float*)d_in[7];
  const float* b1 = (const float*)d_in[8];
  const float* g2 = (const float*)d_in[9];
  const float* b2 = (const float*)d_in[10];
  const float* g3 = (const float*)d_in[11];
  const float* b3 = (const float*)d_in[12];
  const float* g4 = (const float*)d_in[13];
  const float* b4 = (const float*)d_in[14];
  const float* g5 = (const float*)d_in[15];
  const float* b5 = (const float*)d_in[16];

  char* base = (char*)d_ws;
  size_t off = 0;
  auto alloc = [&](size_t bytes) -> char* {
    char* p = base + off;
    off += (bytes + 255) & ~(size_t)255;
    return p;
  };
  double* stAll = (double*)alloc(5 * 1024 * 8);  // 5 disjoint per-layer stat slots
  double* sq = (double*)alloc((size_t)BB * NN * 8);
  double* rnx = (double*)alloc((size_t)BB * NN * 8);
  double* rny = (double*)alloc((size_t)BB * MM * 8);
  int* idxb = (int*)alloc((size_t)BB * NN * KNN * 4);
  int* rowt = (int*)alloc(256 * 4);
  int* colt = (int*)alloc(256 * 4);
  int* pflag = (int*)alloc(256);
  double* xs3d = (double*)alloc((size_t)BB * NN * 3 * 8);
  double* ysd = (double*)alloc((size_t)BB * MM * 128 * 8);
  double* catd = (double*)alloc((size_t)BB * NN * 256 * 8);  // knn channels 0..255
  __hip_bfloat16* cath = (__hip_bfloat16*)alloc((size_t)BB * NN * 512 * 2);
  __hip_bfloat16* w5h = (__hip_bfloat16*)alloc((size_t)512 * 512 * 2);
  double* uu = (double*)alloc((size_t)BB * MM * 256 * 8);  // src term (max O=256)
  double* tt = (double*)alloc((size_t)BB * NN * 256 * 8);  // center term
  size_t kkBatchBytes = (size_t)NN * MM * 8;  // 8 MB per batch (u64 keys)
  size_t avail = (ws_size > off) ? (ws_size - off) : 0;
  int CB = (int)(avail / kkBatchBytes);
  if (CB < 1) CB = 1;
  if (CB > BB) CB = BB;
  u64* KK = (u64*)alloc((size_t)CB * kkBatchBytes);
  float* y5 = (float*)uu;             // layer-5 pre-BN (16MB), uu dead by then
  double* mx = (double*)d_out;        // max_k y (f64, <=16MB == out_size)
  float* outp = (float*)d_out;

  const double cntE = (double)BB * NN * KNN;

  // sym=1: triangular symmetric euclid gram (A==B); else general MODE-2 gram (L4)
  auto knn = [&](const double* A, int lda, const double* Bm, int ldb,
                 const double* sa, const double* sb, int C, int sym) {
    for (int b0 = 0; b0 < BB; b0 += CB) {
      int cb = (BB - b0 < CB) ? (BB - b0) : CB;
      if (sym) {
        k_gram_sym<<<dim3(cb, 136), 64, 0, stream>>>(A, lda, sa, KK, C, b0, rowt, colt,
                                                     pflag);
      } else {
        dim3 g(cb, MM / 64, NN / 64);
        k_gram_u<2><<<g, 64, 0, stream>>>(A, lda, Bm, ldb, sa, sb, KK, C, b0, rowt,
                                          colt, pflag);
      }
      k_topk<<<dim3(cb, 256), 256, 0, stream>>>(KK, idxb, b0);
    }
  };

  // nrmmode: 0 none; 1 -> sq (O=64); 2 -> rnx rsqrt (O=128)
  auto edge_layer = [&](const double* ctr, int ldc, const double* src, int ldsrc,
                        int srcNp, const float* w, int CW, const float* g,
                        const float* bb, int C, int O, int coff, double* st,
                        double* nrmout, int nrmmode) {
    k_featmm2<<<dim3(8, 2 * (O / 64), 16), 256, 0, stream>>>(
        src, ldsrc, srcNp, ctr, ldc, w, CW, uu, tt, C, O, rowt, colt, pflag);
    k_gather<<<dim3(O / 64, NN / 16, BB), 256, 0, stream>>>(uu, tt, idxb, st, mx, O,
                                                            srcNp);
    int gsz = (BB * NN * O + 255) / 256;
    if (nrmmode == 1)
      k_bnapply<1><<<gsz, 256, 0, stream>>>(mx, uu, tt, idxb, st, g, bb, cntE, catd,
                                            cath, coff, O, srcNp, nrmout);
    else if (nrmmode == 2)
      k_bnapply<2><<<gsz, 256, 0, stream>>>(mx, uu, tt, idxb, st, g, bb, cntE, catd,
                                            cath, coff, O, srcNp, nrmout);
    else
      k_bnapply<0><<<gsz, 256, 0, stream>>>(mx, uu, tt, idxb, st, g, bb, cntE, catd,
                                            cath, coff, O, srcNp, nrmout);
  };

  // ---- one upfront memset for ALL stat slots + probe + transposes + w5 bf16 ----
  hipMemsetAsync(stAll, 0, 5 * 1024 * 8, stream);
  k_probe_mfma<<<1, 64, 0, stream>>>(rowt, colt, pflag);
  k_transpose_d<<<96, 256, 0, stream>>>(x, xs3d, 3, NN);
  k_transpose_d<<<2048, 256, 0, stream>>>(y, ysd, 128, MM);
  k_cvt_bf16<<<1024, 256, 0, stream>>>(w5, w5h, 512 * 512);

  // ---- layer 1: C=3, O=64 (fused knn, no gram); bnapply emits sq for L2 ----
  k_rowsq<0><<<32, 256, 0, stream>>>(xs3d, 3, 3, sq);
  k_knn3<<<dim3(BB, 256), 256, 0, stream>>>(xs3d, sq, idxb);
  edge_layer(xs3d, 3, xs3d, 3, NN, w1, 6, g1, b1, 3, 64, 0, stAll, sq, 1);

  // ---- layer 2: x1 = catd[:,0:64], C=64, O=64; bnapply emits sq for L3 ----
  knn(catd, 256, catd, 256, sq, sq, 64, 1);
  edge_layer(catd, 256, catd, 256, NN, w2, 128, g2, b2, 64, 64, 64, stAll + 1024, sq,
             1);

  // ---- layer 3: x2 = catd[:,64:128], C=64, O=128; bnapply emits rnx for L4 ----
  knn(catd + 64, 256, catd + 64, 256, sq, sq, 64, 1);
  edge_layer(catd + 64, 256, catd + 64, 256, NN, w3, 128, g3, b3, 64, 128, 128,
             stAll + 2048, rnx, 2);

  // ---- layer 4 (IA): x3 = catd[:,128:256], src = y (cosine knn), C=128, O=256 ----
  k_rowsq<1><<<32, 256, 0, stream>>>(ysd, 128, 128, rny);
  knn(catd + 128, 256, ysd, 128, rnx, rny, 128, 0);
  edge_layer(catd + 128, 256, ysd, 128, MM, w4, 256, g4, b4, 128, 256, 256,
             stAll + 3072, nullptr, 0);

  // ---- layer 5: bf16-MFMA GEMM (stats fused) -> y5, BN, lrelu, transpose ----
  double* st5 = stAll + 4096;
  k_gemm5_mfma<<<dim3(8, 16, 8), 64, 0, stream>>>(cath, w5h, y5, st5);
  k_final5b<<<dim3(16, 8, 8), 256, 0, stream>>>(y5, st5, g5, b5, outp);
}